// Round 1
// 346.310 us; speedup vs baseline: 1.0070x; 1.0070x over previous
//
#include <hip/hip_runtime.h>
#include <hip/hip_bf16.h>
#include <stdint.h>

#define B_ 16
#define S_ 2048
#define H_ 1024
#define N_ 128
#define M_ (B_*N_)    // 2048
#define K5 5120       // compact: 4 relation slots + Init slot (slot 4)
#define MP 2176       // padded rows: 17 tiles of 128 (class-0 block | class-1 block | pad)

typedef __attribute__((ext_vector_type(8))) short s8vec;   // 8 x bf16 (4 VGPRs)
typedef __attribute__((ext_vector_type(4))) short s4vec;   // 4 x bf16 (2 VGPRs)
typedef __attribute__((ext_vector_type(4))) float f4vec;
typedef __hip_bfloat16 bf16;

// ---------------------------------------------------------------------------
// Kernel 0: per-batch sort by `numbers`, validity count, tie-group flags.
__global__ void k_sort(const int* __restrict__ num_ids, const int* __restrict__ is_resp,
                       const float* __restrict__ numbers,
                       int* __restrict__ sigma, int* __restrict__ newgrp,
                       int* __restrict__ respv, float* __restrict__ denom) {
    int b = blockIdx.x, i = threadIdx.x;
    __shared__ float nums[N_];
    __shared__ int sig[N_];
    __shared__ int cnt;
    float ni = numbers[b*N_ + i];
    int idv = num_ids[b*N_ + i];
    int valid = (idv >= 0) ? 1 : 0;
    nums[i] = ni;
    if (i == 0) cnt = 0;
    __syncthreads();
    int p = 0;
    for (int j = 0; j < N_; ++j) {
        float nj = nums[j];
        p += (nj < ni || (nj == ni && j < i)) ? 1 : 0;   // total order, ties by index
    }
    sig[p] = i;
    atomicAdd(&cnt, valid);
    __syncthreads();
    sigma[b*N_ + i] = sig[i];
    int cur = sig[i];
    int prv = (i > 0) ? sig[i-1] : 0;
    newgrp[b*N_ + i] = (i == 0 || nums[cur] != nums[prv]) ? 1 : 0;
    respv[b*N_ + i] = ((is_resp[b*N_ + i] == 1) ? 1 : 0) | (valid << 1);
    if (i == 0) denom[b] = fmaxf((float)(cnt - 1), 1.0f);
}

// ---------------------------------------------------------------------------
// Kernel 0b: global class partition. Single block, 1024 threads, 2 rows each.
// perm: class-0 rows pack at [0,C0), class-1 at [P0, P0+C1), P0 = ceil128(C0).
__global__ void k_meta(const int* __restrict__ respv, int* __restrict__ aperm,
                       int* __restrict__ iperm, int* __restrict__ meta) {
    __shared__ int s0[1024], s1[1024];
    int t = threadIdx.x;
    aperm[t] = -1; aperm[t + 1024] = -1;
    if (t < MP - 2048) aperm[t + 2048] = -1;
    int r0 = 2*t, r1 = 2*t + 1;
    int c_a = respv[r0] & 1, c_b = respv[r1] & 1;
    int a0 = 1 - c_a, b0 = 1 - c_b;
    s0[t] = a0 + b0;
    s1[t] = c_a + c_b;
    __syncthreads();
    for (int off = 1; off < 1024; off <<= 1) {
        int v0 = (t >= off) ? s0[t-off] : 0;
        int v1 = (t >= off) ? s1[t-off] : 0;
        __syncthreads();
        s0[t] += v0; s1[t] += v1;
        __syncthreads();
    }
    int C0 = s0[1023], C1 = s1[1023];
    int P0 = ((C0 + 127) >> 7) << 7;
    int ex0 = s0[t] - (a0 + b0);     // exclusive prefix over pairs
    int ex1 = s1[t] - (c_a + c_b);
    int p_a = (c_a == 0) ? ex0 : P0 + ex1;
    int p_b = (c_b == 0) ? ex0 + a0 : P0 + ex1 + c_a;
    aperm[p_a] = r0; iperm[r0] = p_a;
    aperm[p_b] = r1; iperm[r1] = p_b;
    if (t == 0) { meta[0] = P0; meta[1] = C0; meta[2] = C1; }
}

// ---------------------------------------------------------------------------
// Kernel 1: gather Init, alpha = sigmoid(Init.w_alpha), Init -> A[pr] slot 4,
// ascaled = valid * alpha / denom. Packed 8B bf16 store.
__global__ void k_gather(const float* __restrict__ word_emb, const int* __restrict__ num_ids,
                         const float* __restrict__ w_alpha, const float* __restrict__ b_alpha,
                         const float* __restrict__ denom, const int* __restrict__ iperm,
                         bf16* __restrict__ A, float* __restrict__ ascaled) {
    int blk = blockIdx.x;
    int b = blk >> 7, n = blk & 127;
    int t = threadIdx.x;
    int idv = num_ids[b*N_ + n];
    int valid = (idv >= 0) ? 1 : 0;
    int idx = idv < 0 ? 0 : (idv > S_-1 ? S_-1 : idv);
    int pr = iperm[b*N_ + n];
    const float4* row = (const float4*)(word_emb + ((size_t)b*S_ + idx)*H_);
    float4 v = row[t];
    float4 w = ((const float4*)w_alpha)[t];
    float part = v.x*w.x + v.y*w.y + v.z*w.z + v.w*w.w;
    union { s4vec v4; bf16 h[4]; } pk;
    pk.h[0] = __float2bfloat16(v.x);
    pk.h[1] = __float2bfloat16(v.y);
    pk.h[2] = __float2bfloat16(v.z);
    pk.h[3] = __float2bfloat16(v.w);
    *(s4vec*)(A + (size_t)pr*K5 + 4*H_ + t*4) = pk.v4;
#pragma unroll
    for (int off = 32; off > 0; off >>= 1) part += __shfl_down(part, off, 64);
    __shared__ float red[4];
    if ((t & 63) == 0) red[t >> 6] = part;
    __syncthreads();
    if (t == 0) {
        float dot = red[0] + red[1] + red[2] + red[3] + b_alpha[0];
        float al = 1.0f / (1.0f + __expf(-dot));
        ascaled[b*N_ + n] = valid ? (al / denom[b]) : 0.0f;
    }
}

// ---------------------------------------------------------------------------
// Kernel 2a: W_r -> Wt[class][slot 0..3]. r = 4*(s>>1) + 2*c + (s&1).
// 8 elems/thread, single 16B bf16 store. 4096 blocks.
__global__ void k_wt(const float* __restrict__ W_r, bf16* __restrict__ Wt) {
    size_t o = ((size_t)blockIdx.x*256 + threadIdx.x)*8;   // over 2*4*H*H elems
    int cs = (int)(o >> 20);                               // H*H = 2^20
    int c = cs >> 2, s = cs & 3;
    int r = ((s >> 1) << 2) + 2*c + (s & 1);
    size_t off = o & (size_t)(H_*H_ - 1);
    const float4* src = (const float4*)(W_r + (size_t)r*H_*H_ + off);
    float4 v0 = src[0], v1 = src[1];
    union { s8vec v8; bf16 h[8]; } pk;
    pk.h[0] = __float2bfloat16(v0.x); pk.h[1] = __float2bfloat16(v0.y);
    pk.h[2] = __float2bfloat16(v0.z); pk.h[3] = __float2bfloat16(v0.w);
    pk.h[4] = __float2bfloat16(v1.x); pk.h[5] = __float2bfloat16(v1.y);
    pk.h[6] = __float2bfloat16(v1.z); pk.h[7] = __float2bfloat16(v1.w);
    *(s8vec*)(Wt + (size_t)(c*5 + s)*H_*H_ + off) = pk.v8;
}

// Kernel 2b: w_f [k][n] -> slot 4 as [n][k] in BOTH class stacks. LDS transpose,
// packed 8B stores.
__global__ void k_wf(const float* __restrict__ w_f, bf16* __restrict__ Wt) {
    __shared__ float lds[64][65];
    int bi = blockIdx.x, bj = blockIdx.y;
    int t = threadIdx.x;
    int ty = t >> 4, tx = t & 15;
#pragma unroll
    for (int i = 0; i < 4; ++i) {
        int r = ty*4 + i;                                    // k index within tile
        float4 v = *(const float4*)(w_f + (size_t)(bi*64 + r)*H_ + bj*64 + tx*4);
        lds[r][tx*4+0] = v.x; lds[r][tx*4+1] = v.y;
        lds[r][tx*4+2] = v.z; lds[r][tx*4+3] = v.w;
    }
    __syncthreads();
    bf16* d0 = Wt + (size_t)4*H_*H_;        // class 0 slot 4
    bf16* d1 = Wt + (size_t)9*H_*H_;        // class 1 slot 4
#pragma unroll
    for (int i = 0; i < 4; ++i) {
        int n = ty*4 + i;
        size_t doff = (size_t)(bj*64 + n)*H_ + bi*64 + tx*4;
        union { s4vec v4; bf16 h[4]; } pk;
#pragma unroll
        for (int j = 0; j < 4; ++j) pk.h[j] = __float2bfloat16(lds[tx*4+j][n]);
        *(s4vec*)(d0 + doff) = pk.v4;
        *(s4vec*)(d1 + doff) = pk.v4;
    }
}

// ---------------------------------------------------------------------------
// Kernel 3: build A slots 0-3 via prefix sums over sorted order.
// Compact layout: s0=L0, s1=L1, s2=G0, s3=G1 (class picks the weight stack).
__global__ void k_build(const float* __restrict__ ascaled, const int* __restrict__ sigma,
                        const int* __restrict__ newgrp, const int* __restrict__ respv,
                        const int* __restrict__ iperm, bf16* __restrict__ A) {
    int b = blockIdx.y;
    int h = blockIdx.x*64 + threadIdx.x;
    __shared__ float as_s[N_];
    __shared__ int sig_s[N_], ng_s[N_], rv_s[N_], pm_s[N_];
    for (int j = threadIdx.x; j < N_; j += 64) {
        as_s[j] = ascaled[b*N_ + j];
        sig_s[j] = sigma[b*N_ + j];
        ng_s[j] = newgrp[b*N_ + j];
        rv_s[j] = respv[b*N_ + j];
        pm_s[j] = iperm[b*N_ + j];
    }
    __syncthreads();
    const bf16* initcol = A + 4*H_ + h;          // + pr*K5
    float tot0 = 0.f, tot1 = 0.f;
    for (int i2 = 0; i2 < N_; ++i2) {
        float v = as_s[i2] * __bfloat162float(initcol[(size_t)pm_s[i2]*K5]);
        if (rv_s[i2] & 1) tot1 += v; else tot0 += v;
    }
    float cS0=0.f, cS1=0.f, cG0=0.f, cG1=0.f;   // strict prefix + current tie group
    for (int p = 0; p < N_; ++p) {
        int i2 = sig_s[p];
        if (ng_s[p]) { cS0 += cG0; cS1 += cG1; cG0 = 0.f; cG1 = 0.f; }
        float v = as_s[i2] * __bfloat162float(initcol[(size_t)pm_s[i2]*K5]);
        int resp = rv_s[i2] & 1;
        float vf = (rv_s[i2] >> 1) ? 1.0f : 0.0f;
        float G0 = cS0, G1 = cS1;                    // senders with num_j < num_i
        float L0 = tot0 - G0 - (resp ? 0.f : v);     // num_j >= num_i, j != i
        float L1 = tot1 - G1 - (resp ? v : 0.f);
        bf16* Ar = A + (size_t)pm_s[i2]*K5 + h;
        Ar[0*H_] = __float2bfloat16(L0*vf);
        Ar[1*H_] = __float2bfloat16(L1*vf);
        Ar[2*H_] = __float2bfloat16(G0*vf);
        Ar[3*H_] = __float2bfloat16(G1*vf);
        if (resp) cG1 += v; else cG0 += v;
    }
}

// ---------------------------------------------------------------------------
// Kernel 4: GEMM out[2176,1024] = A[2176,5120] x Wt_class^T, fused epilogue.
// NO split-K, NO atomics: 17x8 = 136 blocks of BM=BN=128, full K=5120 walked
// in 80 BK=64 steps. Double-buffered LDS (64 KB), ONE barrier per step:
//   barrier -> issue next-step global_load_lds -> ds_read+MFMA current -> ...
// so the vmcnt(0) drain at each __syncthreads happens AFTER a full MFMA phase
// (loads fly under compute). Staging: row-contiguous 16B chunks, 8 pieces per
// 128B row, XOR swizzle p = sp ^ (row&7); row stride = 128 B = exactly 32
// banks, so slot spread alone balances ds_read_b128 banks.
// Grid swizzle: XCD x owns output column nt=x -> its 1.31 MB B-panel is
// L2-resident. Epilogue: bias+relu+aperm-scatter direct stores (pad rows,
// aperm<0, are simply not stored -> k_pad/memset/k_epi all unnecessary).
#define BM 128
#define BN 128
#define BK 64
#define NSTEP (K5/BK)   // 80

__global__ __launch_bounds__(256) void k_gemm(const bf16* __restrict__ A,
                                              const bf16* __restrict__ Wt,
                                              const int* __restrict__ meta,
                                              const int* __restrict__ aperm,
                                              const float* __restrict__ b_f,
                                              float* __restrict__ out) {
    __shared__ __align__(16) bf16 As0[BM*BK], As1[BM*BK];   // 16 KB each
    __shared__ __align__(16) bf16 Bs0[BN*BK], Bs1[BN*BK];
    int tid = threadIdx.x;
    int w = tid >> 6, lane = tid & 63;
    int q = lane >> 4, r = lane & 15;
    int bid = blockIdx.x;
    int wg = (bid & 7)*17 + (bid >> 3);      // 136 = 8x17 bijective; XCD x -> nt=x
    int mt = wg % 17, nt = wg / 17;
    int rowBase = mt * BM, colBase = nt * BN;
    int wm = w >> 1, wn = w & 1;
    int P0 = meta[0];
    const bf16* Wtc = Wt + ((rowBase >= P0) ? (size_t)5*H_*H_ : 0);

    f4vec acc[4][4];
#pragma unroll
    for (int mi = 0; mi < 4; ++mi)
#pragma unroll
        for (int ni = 0; ni < 4; ++ni)
#pragma unroll
            for (int e = 0; e < 4; ++e) acc[mi][ni][e] = 0.0f;

    auto STAGE = [&](bf16* AsB, bf16* BsB, int kin) {
        int slot = kin >> 10, koff = kin & 1023;
        const bf16* Wslot = Wtc + ((size_t)slot << 20);
#pragma unroll
        for (int j = 0; j < 4; ++j) {
            int c = tid + j*256;              // chunk id 0..1023 (16B each)
            int row = c >> 3;
            int p = (c & 7) ^ (row & 7);      // global piece -> LDS slot c&7
            const bf16* ga = A + (size_t)(rowBase + row)*K5 + kin + p*8;
            __builtin_amdgcn_global_load_lds((const __attribute__((address_space(1))) void*)ga,
                (__attribute__((address_space(3))) void*)((char*)AsB + j*4096 + w*1024), 16, 0, 0);
            const bf16* gb = Wslot + ((size_t)(colBase + row) << 10) + koff + p*8;
            __builtin_amdgcn_global_load_lds((const __attribute__((address_space(1))) void*)gb,
                (__attribute__((address_space(3))) void*)((char*)BsB + j*4096 + w*1024), 16, 0, 0);
        }
    };

    auto COMPUTE = [&](const bf16* AsB, const bf16* BsB) {
        const short* Asp = (const short*)AsB;
        const short* Bsp = (const short*)BsB;
        s8vec af[2][4], bfr[2][4];
#pragma unroll
        for (int kk = 0; kk < 2; ++kk) {
            int sl = ((kk*4 + q) ^ (r & 7)) << 3;    // slot = piece ^ (row&7), row&7 = r&7
#pragma unroll
            for (int mi = 0; mi < 4; ++mi)
                af[kk][mi] = *(const s8vec*)(Asp + (wm*64 + mi*16 + r)*BK + sl);
#pragma unroll
            for (int ni = 0; ni < 4; ++ni)
                bfr[kk][ni] = *(const s8vec*)(Bsp + (wn*64 + ni*16 + r)*BK + sl);
        }
#pragma unroll
        for (int kk = 0; kk < 2; ++kk)
#pragma unroll
            for (int mi = 0; mi < 4; ++mi)
#pragma unroll
                for (int ni = 0; ni < 4; ++ni)
                    acc[mi][ni] = __builtin_amdgcn_mfma_f32_16x16x32_bf16(
                        af[kk][mi], bfr[kk][ni], acc[mi][ni], 0, 0, 0);
    };

    STAGE(As0, Bs0, 0);
    for (int t = 0; t < NSTEP; t += 2) {
        __syncthreads();                                   // drain buf0 loads
        if (t + 1 < NSTEP) STAGE(As1, Bs1, (t+1)*BK);      // prefetch under compute
        COMPUTE(As0, Bs0);
        __syncthreads();                                   // drain buf1 loads
        if (t + 2 < NSTEP) STAGE(As0, Bs0, (t+2)*BK);
        COMPUTE(As1, Bs1);
    }

    // Fused epilogue: bias + relu + aperm row-scatter. Pad rows skipped.
    float bias[4];
#pragma unroll
    for (int ni = 0; ni < 4; ++ni) bias[ni] = b_f[colBase + wn*64 + ni*16 + r];
#pragma unroll
    for (int mi = 0; mi < 4; ++mi) {
        int rb = rowBase + wm*64 + mi*16 + q*4;            // D row = q*4+e
        int og0 = aperm[rb+0], og1 = aperm[rb+1], og2 = aperm[rb+2], og3 = aperm[rb+3];
#pragma unroll
        for (int ni = 0; ni < 4; ++ni) {
            int cc = colBase + wn*64 + ni*16 + r;          // D col = lane&15
            if (og0 >= 0) out[(size_t)og0*H_ + cc] = fmaxf(acc[mi][ni][0] + bias[ni], 0.0f);
            if (og1 >= 0) out[(size_t)og1*H_ + cc] = fmaxf(acc[mi][ni][1] + bias[ni], 0.0f);
            if (og2 >= 0) out[(size_t)og2*H_ + cc] = fmaxf(acc[mi][ni][2] + bias[ni], 0.0f);
            if (og3 >= 0) out[(size_t)og3*H_ + cc] = fmaxf(acc[mi][ni][3] + bias[ni], 0.0f);
        }
    }
}

// ---------------------------------------------------------------------------
extern "C" void kernel_launch(void* const* d_in, const int* in_sizes, int n_in,
                              void* d_out, int out_size, void* d_ws, size_t ws_size,
                              hipStream_t stream) {
    (void)in_sizes; (void)n_in; (void)out_size; (void)ws_size;
    const float* word_emb = (const float*)d_in[0];
    const int*   num_ids  = (const int*)d_in[1];
    const int*   is_resp  = (const int*)d_in[2];
    const float* numbers  = (const float*)d_in[3];
    const float* w_alpha  = (const float*)d_in[4];
    const float* b_alpha  = (const float*)d_in[5];
    const float* w_f      = (const float*)d_in[6];
    const float* b_f      = (const float*)d_in[7];
    const float* W_r      = (const float*)d_in[8];
    float* out = (float*)d_out;

    char* ws = (char*)d_ws;
    bf16*  Aws     = (bf16*)(ws);                    // [2176][5120] = 22,282,240 B
    bf16*  Wt      = (bf16*)(ws + 22282240);         // [2][5][1024][1024] = 20,971,520 B
    float* ascaled = (float*)(ws + 52166656);
    int*   sigma   = (int*)(ws + 52174848);
    int*   newgrp  = (int*)(ws + 52183040);
    int*   respv   = (int*)(ws + 52191232);
    float* denom   = (float*)(ws + 52199424);
    int*   aperm   = (int*)(ws + 52199488);          // [2176]
    int*   iperm   = (int*)(ws + 52208192);          // [2048]
    int*   meta    = (int*)(ws + 52216384);          // [4]

    k_sort  <<<16,   128, 0, stream>>>(num_ids, is_resp, numbers, sigma, newgrp, respv, denom);
    k_meta  <<<1,   1024, 0, stream>>>(respv, aperm, iperm, meta);
    k_gather<<<2048, 256, 0, stream>>>(word_emb, num_ids, w_alpha, b_alpha, denom, iperm,
                                       Aws, ascaled);
    k_wt    <<<4096, 256, 0, stream>>>(W_r, Wt);
    k_wf    <<<dim3(16,16), 256, 0, stream>>>(w_f, Wt);
    k_build <<<dim3(16,16), 64, 0, stream>>>(ascaled, sigma, newgrp, respv, iperm, Aws);
    k_gemm  <<<136,  256, 0, stream>>>(Aws, Wt, meta, aperm, b_f, out);
}

// Round 3
// 322.377 us; speedup vs baseline: 1.0818x; 1.0742x over previous
//
#include <hip/hip_runtime.h>
#include <hip/hip_bf16.h>
#include <stdint.h>

#define B_ 16
#define S_ 2048
#define H_ 1024
#define N_ 128
#define M_ (B_*N_)    // 2048
#define K5 5120       // compact: 4 relation slots + Init slot (slot 4)
#define MP 2176       // padded rows: 17 tiles of 128 (class-0 block | class-1 block | pad)

typedef __attribute__((ext_vector_type(8))) short s8vec;   // 8 x bf16 (4 VGPRs)
typedef __attribute__((ext_vector_type(4))) short s4vec;   // 4 x bf16 (2 VGPRs)
typedef __attribute__((ext_vector_type(4))) float f4vec;
typedef __hip_bfloat16 bf16;

// ---------------------------------------------------------------------------
// Kernel 0: per-batch sort by `numbers`, validity count, tie-group flags.
__global__ void k_sort(const int* __restrict__ num_ids, const int* __restrict__ is_resp,
                       const float* __restrict__ numbers,
                       int* __restrict__ sigma, int* __restrict__ newgrp,
                       int* __restrict__ respv, float* __restrict__ denom) {
    int b = blockIdx.x, i = threadIdx.x;
    __shared__ float nums[N_];
    __shared__ int sig[N_];
    __shared__ int cnt;
    float ni = numbers[b*N_ + i];
    int idv = num_ids[b*N_ + i];
    int valid = (idv >= 0) ? 1 : 0;
    nums[i] = ni;
    if (i == 0) cnt = 0;
    __syncthreads();
    int p = 0;
    for (int j = 0; j < N_; ++j) {
        float nj = nums[j];
        p += (nj < ni || (nj == ni && j < i)) ? 1 : 0;   // total order, ties by index
    }
    sig[p] = i;
    atomicAdd(&cnt, valid);
    __syncthreads();
    sigma[b*N_ + i] = sig[i];
    int cur = sig[i];
    int prv = (i > 0) ? sig[i-1] : 0;
    newgrp[b*N_ + i] = (i == 0 || nums[cur] != nums[prv]) ? 1 : 0;
    respv[b*N_ + i] = ((is_resp[b*N_ + i] == 1) ? 1 : 0) | (valid << 1);
    if (i == 0) denom[b] = fmaxf((float)(cnt - 1), 1.0f);
}

// ---------------------------------------------------------------------------
// Kernel 0b: global class partition. Single block, 1024 threads, 2 rows each.
// perm: class-0 rows pack at [0,C0), class-1 at [P0, P0+C1), P0 = ceil128(C0).
__global__ void k_meta(const int* __restrict__ respv, int* __restrict__ aperm,
                       int* __restrict__ iperm, int* __restrict__ meta) {
    __shared__ int s0[1024], s1[1024];
    int t = threadIdx.x;
    aperm[t] = -1; aperm[t + 1024] = -1;
    if (t < MP - 2048) aperm[t + 2048] = -1;
    int r0 = 2*t, r1 = 2*t + 1;
    int c_a = respv[r0] & 1, c_b = respv[r1] & 1;
    int a0 = 1 - c_a, b0 = 1 - c_b;
    s0[t] = a0 + b0;
    s1[t] = c_a + c_b;
    __syncthreads();
    for (int off = 1; off < 1024; off <<= 1) {
        int v0 = (t >= off) ? s0[t-off] : 0;
        int v1 = (t >= off) ? s1[t-off] : 0;
        __syncthreads();
        s0[t] += v0; s1[t] += v1;
        __syncthreads();
    }
    int C0 = s0[1023], C1 = s1[1023];
    int P0 = ((C0 + 127) >> 7) << 7;
    int ex0 = s0[t] - (a0 + b0);     // exclusive prefix over pairs
    int ex1 = s1[t] - (c_a + c_b);
    int p_a = (c_a == 0) ? ex0 : P0 + ex1;
    int p_b = (c_b == 0) ? ex0 + a0 : P0 + ex1 + c_a;
    aperm[p_a] = r0; iperm[r0] = p_a;
    aperm[p_b] = r1; iperm[r1] = p_b;
    if (t == 0) { meta[0] = P0; meta[1] = C0; meta[2] = C1; }
}

// ---------------------------------------------------------------------------
// Kernel 1: gather Init, alpha = sigmoid(Init.w_alpha), Init -> A[pr] slot 4,
// ascaled = valid * alpha / denom. Packed 8B bf16 store.
__global__ void k_gather(const float* __restrict__ word_emb, const int* __restrict__ num_ids,
                         const float* __restrict__ w_alpha, const float* __restrict__ b_alpha,
                         const float* __restrict__ denom, const int* __restrict__ iperm,
                         bf16* __restrict__ A, float* __restrict__ ascaled) {
    int blk = blockIdx.x;
    int b = blk >> 7, n = blk & 127;
    int t = threadIdx.x;
    int idv = num_ids[b*N_ + n];
    int valid = (idv >= 0) ? 1 : 0;
    int idx = idv < 0 ? 0 : (idv > S_-1 ? S_-1 : idv);
    int pr = iperm[b*N_ + n];
    const float4* row = (const float4*)(word_emb + ((size_t)b*S_ + idx)*H_);
    float4 v = row[t];
    float4 w = ((const float4*)w_alpha)[t];
    float part = v.x*w.x + v.y*w.y + v.z*w.z + v.w*w.w;
    union { s4vec v4; bf16 h[4]; } pk;
    pk.h[0] = __float2bfloat16(v.x);
    pk.h[1] = __float2bfloat16(v.y);
    pk.h[2] = __float2bfloat16(v.z);
    pk.h[3] = __float2bfloat16(v.w);
    *(s4vec*)(A + (size_t)pr*K5 + 4*H_ + t*4) = pk.v4;
#pragma unroll
    for (int off = 32; off > 0; off >>= 1) part += __shfl_down(part, off, 64);
    __shared__ float red[4];
    if ((t & 63) == 0) red[t >> 6] = part;
    __syncthreads();
    if (t == 0) {
        float dot = red[0] + red[1] + red[2] + red[3] + b_alpha[0];
        float al = 1.0f / (1.0f + __expf(-dot));
        ascaled[b*N_ + n] = valid ? (al / denom[b]) : 0.0f;
    }
}

// ---------------------------------------------------------------------------
// Kernel 2: merged weight prep (one launch).
//  bid < 4096 : W_r -> Wt[class][slot 0..3], r = 4*(s>>1)+2*c+(s&1), 8 elem/thr.
//  bid >= 4096: w_f [k][n] -> slot 4 as [n][k] in BOTH class stacks (LDS transpose).
__global__ void k_wtf(const float* __restrict__ W_r, const float* __restrict__ w_f,
                      bf16* __restrict__ Wt) {
    __shared__ float lds[64][65];
    int bid = blockIdx.x;
    int t = threadIdx.x;
    if (bid < 4096) {
        size_t o = ((size_t)bid*256 + t)*8;                // over 2*4*H*H elems
        int cs = (int)(o >> 20);                           // H*H = 2^20
        int c = cs >> 2, s = cs & 3;
        int r = ((s >> 1) << 2) + 2*c + (s & 1);
        size_t off = o & (size_t)(H_*H_ - 1);
        const float4* src = (const float4*)(W_r + (size_t)r*H_*H_ + off);
        float4 v0 = src[0], v1 = src[1];
        union { s8vec v8; bf16 h[8]; } pk;
        pk.h[0] = __float2bfloat16(v0.x); pk.h[1] = __float2bfloat16(v0.y);
        pk.h[2] = __float2bfloat16(v0.z); pk.h[3] = __float2bfloat16(v0.w);
        pk.h[4] = __float2bfloat16(v1.x); pk.h[5] = __float2bfloat16(v1.y);
        pk.h[6] = __float2bfloat16(v1.z); pk.h[7] = __float2bfloat16(v1.w);
        *(s8vec*)(Wt + (size_t)(c*5 + s)*H_*H_ + off) = pk.v8;
        return;
    }
    int bb = bid - 4096;
    int bi = bb & 15, bj = bb >> 4;
    int ty = t >> 4, tx = t & 15;
#pragma unroll
    for (int i = 0; i < 4; ++i) {
        int r = ty*4 + i;                                    // k index within tile
        float4 v = *(const float4*)(w_f + (size_t)(bi*64 + r)*H_ + bj*64 + tx*4);
        lds[r][tx*4+0] = v.x; lds[r][tx*4+1] = v.y;
        lds[r][tx*4+2] = v.z; lds[r][tx*4+3] = v.w;
    }
    __syncthreads();
    bf16* d0 = Wt + (size_t)4*H_*H_;        // class 0 slot 4
    bf16* d1 = Wt + (size_t)9*H_*H_;        // class 1 slot 4
#pragma unroll
    for (int i = 0; i < 4; ++i) {
        int n = ty*4 + i;
        size_t doff = (size_t)(bj*64 + n)*H_ + bi*64 + tx*4;
        union { s4vec v4; bf16 h[4]; } pk;
#pragma unroll
        for (int j = 0; j < 4; ++j) pk.h[j] = __float2bfloat16(lds[tx*4+j][n]);
        *(s4vec*)(d0 + doff) = pk.v4;
        *(s4vec*)(d1 + doff) = pk.v4;
    }
}

// ---------------------------------------------------------------------------
// Kernel 3: build A slots 0-3 via prefix sums over sorted order. Round-1 rolling
// form (known-good); partial unroll 8 so independent global loads pipeline
// (8 in flight -> ~1/8 the serial-load latency). No big per-thread arrays.
__global__ void k_build(const float* __restrict__ ascaled, const int* __restrict__ sigma,
                        const int* __restrict__ newgrp, const int* __restrict__ respv,
                        const int* __restrict__ iperm, bf16* __restrict__ A) {
    int b = blockIdx.y;
    int h = blockIdx.x*64 + threadIdx.x;
    __shared__ float as_s[N_];
    __shared__ int sig_s[N_], ng_s[N_], rv_s[N_], pm_s[N_];
    for (int j = threadIdx.x; j < N_; j += 64) {
        as_s[j] = ascaled[b*N_ + j];
        sig_s[j] = sigma[b*N_ + j];
        ng_s[j] = newgrp[b*N_ + j];
        rv_s[j] = respv[b*N_ + j];
        pm_s[j] = iperm[b*N_ + j];
    }
    __syncthreads();
    const bf16* initcol = A + 4*H_ + h;          // + pr*K5
    float tot0 = 0.f, tot1 = 0.f;
#pragma unroll 8
    for (int i2 = 0; i2 < N_; ++i2) {
        float v = as_s[i2] * __bfloat162float(initcol[(size_t)pm_s[i2]*K5]);
        if (rv_s[i2] & 1) tot1 += v; else tot0 += v;
    }
    float cS0=0.f, cS1=0.f, cG0=0.f, cG1=0.f;   // strict prefix + current tie group
#pragma unroll 8
    for (int p = 0; p < N_; ++p) {
        int i2 = sig_s[p];
        if (ng_s[p]) { cS0 += cG0; cS1 += cG1; cG0 = 0.f; cG1 = 0.f; }
        float v = as_s[i2] * __bfloat162float(initcol[(size_t)pm_s[i2]*K5]);
        int resp = rv_s[i2] & 1;
        float vf = (rv_s[i2] >> 1) ? 1.0f : 0.0f;
        float G0 = cS0, G1 = cS1;                    // senders with num_j < num_i
        float L0 = tot0 - G0 - (resp ? 0.f : v);     // num_j >= num_i, j != i
        float L1 = tot1 - G1 - (resp ? v : 0.f);
        bf16* Ar = A + (size_t)pm_s[i2]*K5 + h;
        Ar[0*H_] = __float2bfloat16(L0*vf);
        Ar[1*H_] = __float2bfloat16(L1*vf);
        Ar[2*H_] = __float2bfloat16(G0*vf);
        Ar[3*H_] = __float2bfloat16(G1*vf);
        if (resp) cG1 += v; else cG0 += v;
    }
}

// ---------------------------------------------------------------------------
// Kernel 4: GEMM out[2176,1024] = A[2176,5120] x Wt_class^T, fused epilogue.
// 64x64 tiles -> 544 blocks (2-3/CU, 8-12 waves/CU TLP) + 3-deep LDS pipeline
// with COUNTED vmcnt: stage t+2 loads stay in flight across the raw s_barrier;
// each wave drains only its OWN oldest stage (vmcnt(4), in-order VMEM
// retirement) BEFORE the barrier => barrier arrival == all waves' stage-t
// data landed. Epilogue aperm/b_f are loaded and force-materialized BEFORE
// the first STAGE so the loop's VMEM stream is exactly the 4-loads-per-stage
// the vmcnt counting assumes. sched_barrier(0) after the barrier pins ds_reads
// below it (rule #18). XOR piece swizzle (0 conflicts measured round 1).
// XCD swizzle: 544 = 8x68; XCD x owns col-pair {2x,2x+1}.
#define BM 64
#define BN 64
#define BK 64
#define NSTEP (K5/BK)   // 80

__global__ __launch_bounds__(256, 3) void k_gemm(const bf16* __restrict__ A,
                                                 const bf16* __restrict__ Wt,
                                                 const int* __restrict__ meta,
                                                 const int* __restrict__ aperm,
                                                 const float* __restrict__ b_f,
                                                 float* __restrict__ out) {
    __shared__ __align__(16) bf16 As0[BM*BK], As1[BM*BK], As2[BM*BK];   // 8 KB each
    __shared__ __align__(16) bf16 Bs0[BN*BK], Bs1[BN*BK], Bs2[BN*BK];
    int tid = threadIdx.x;
    int w = tid >> 6, lane = tid & 63;
    int q = lane >> 4, r = lane & 15;
    int bid = blockIdx.x;
    int wg = (bid & 7)*68 + (bid >> 3);      // 544 = 8x68 bijective; XCD x -> nt in {2x,2x+1}
    int mt = wg % 34, nt = wg / 34;
    int rowBase = mt * BM, colBase = nt * BN;
    int wm = w >> 1, wn = w & 1;             // wave tile 32x32
    int P0 = meta[0];
    const bf16* Wtc = Wt + ((rowBase >= P0) ? (size_t)5*H_*H_ : 0);

    // ---- epilogue operands loaded UP FRONT and pinned, so the main loop's
    // VMEM stream is pure stage traffic (exact vmcnt accounting).
    int og[2][4];
    float bias[2];
#pragma unroll
    for (int mi = 0; mi < 2; ++mi) {
        int rb = rowBase + wm*32 + mi*16 + q*4;
#pragma unroll
        for (int e = 0; e < 4; ++e) og[mi][e] = aperm[rb + e];
    }
#pragma unroll
    for (int ni = 0; ni < 2; ++ni) bias[ni] = b_f[colBase + wn*32 + ni*16 + r];
#pragma unroll
    for (int mi = 0; mi < 2; ++mi)
#pragma unroll
        for (int e = 0; e < 4; ++e) asm volatile("" : "+v"(og[mi][e]));
    asm volatile("" : "+v"(bias[0]), "+v"(bias[1]));

    f4vec acc[2][2];
#pragma unroll
    for (int mi = 0; mi < 2; ++mi)
#pragma unroll
        for (int ni = 0; ni < 2; ++ni)
#pragma unroll
            for (int e = 0; e < 4; ++e) acc[mi][ni][e] = 0.0f;

    // 4 global_load_lds per thread per stage (A x2, B x2); two stages in
    // flight => s_waitcnt vmcnt(4) drains exactly the oldest stage.
    auto STAGE = [&](bf16* AsB, bf16* BsB, int kin) {
        int slot = kin >> 10, koff = kin & 1023;
        const bf16* Wslot = Wtc + ((size_t)slot << 20);
#pragma unroll
        for (int j = 0; j < 2; ++j) {
            int c = tid + j*256;              // chunk id 0..511 (16B each)
            int row = c >> 3;
            int p = (c & 7) ^ (row & 7);      // global piece -> LDS slot c&7
            const bf16* ga = A + (size_t)(rowBase + row)*K5 + kin + p*8;
            __builtin_amdgcn_global_load_lds((const __attribute__((address_space(1))) void*)ga,
                (__attribute__((address_space(3))) void*)((char*)AsB + j*4096 + w*1024), 16, 0, 0);
            const bf16* gb = Wslot + ((size_t)(colBase + row) << 10) + koff + p*8;
            __builtin_amdgcn_global_load_lds((const __attribute__((address_space(1))) void*)gb,
                (__attribute__((address_space(3))) void*)((char*)BsB + j*4096 + w*1024), 16, 0, 0);
        }
    };

    auto COMPUTE = [&](const bf16* AsB, const bf16* BsB) {
        const short* Asp = (const short*)AsB;
        const short* Bsp = (const short*)BsB;
        s8vec af[2][2], bfr[2][2];
#pragma unroll
        for (int kk = 0; kk < 2; ++kk) {
            int sl = ((kk*4 + q) ^ (r & 7)) << 3;    // slot = piece ^ (row&7), row&7 = r&7
#pragma unroll
            for (int mi = 0; mi < 2; ++mi)
                af[kk][mi] = *(const s8vec*)(Asp + (wm*32 + mi*16 + r)*BK + sl);
#pragma unroll
            for (int ni = 0; ni < 2; ++ni)
                bfr[kk][ni] = *(const s8vec*)(Bsp + (wn*32 + ni*16 + r)*BK + sl);
        }
#pragma unroll
        for (int kk = 0; kk < 2; ++kk)
#pragma unroll
            for (int mi = 0; mi < 2; ++mi)
#pragma unroll
                for (int ni = 0; ni < 2; ++ni)
                    acc[mi][ni] = __builtin_amdgcn_mfma_f32_16x16x32_bf16(
                        af[kk][mi], bfr[kk][ni], acc[mi][ni], 0, 0, 0);
    };

    STAGE(As0, Bs0, 0);
    STAGE(As1, Bs1, BK);
    bf16 *cA = As0, *cB = Bs0;     // compute buffer (step t)
    bf16 *nA = As1, *nB = Bs1;     // in-flight (step t+1)
    bf16 *sA = As2, *sB = Bs2;     // stage target (step t+2)
    for (int t = 0; t < NSTEP; ++t) {
        if (t + 1 < NSTEP) asm volatile("s_waitcnt vmcnt(4)" ::: "memory");
        else               asm volatile("s_waitcnt vmcnt(0)" ::: "memory");
        __builtin_amdgcn_s_barrier();            // => ALL waves' stage-t landed
        __builtin_amdgcn_sched_barrier(0);       // nothing moves above this line
        if (t + 2 < NSTEP) STAGE(sA, sB, (t + 2)*BK);
        COMPUTE(cA, cB);
        bf16* tA = cA; cA = nA; nA = sA; sA = tA;
        bf16* tB = cB; cB = nB; nB = sB; sB = tB;
    }

    // Fused epilogue: bias + relu + aperm row-scatter. Pad rows skipped.
#pragma unroll
    for (int mi = 0; mi < 2; ++mi) {
#pragma unroll
        for (int ni = 0; ni < 2; ++ni) {
            int cc = colBase + wn*32 + ni*16 + r;          // D col = lane&15
            if (og[mi][0] >= 0) out[(size_t)og[mi][0]*H_ + cc] = fmaxf(acc[mi][ni][0] + bias[ni], 0.0f);
            if (og[mi][1] >= 0) out[(size_t)og[mi][1]*H_ + cc] = fmaxf(acc[mi][ni][1] + bias[ni], 0.0f);
            if (og[mi][2] >= 0) out[(size_t)og[mi][2]*H_ + cc] = fmaxf(acc[mi][ni][2] + bias[ni], 0.0f);
            if (og[mi][3] >= 0) out[(size_t)og[mi][3]*H_ + cc] = fmaxf(acc[mi][ni][3] + bias[ni], 0.0f);
        }
    }
}

// ---------------------------------------------------------------------------
extern "C" void kernel_launch(void* const* d_in, const int* in_sizes, int n_in,
                              void* d_out, int out_size, void* d_ws, size_t ws_size,
                              hipStream_t stream) {
    (void)in_sizes; (void)n_in; (void)out_size; (void)ws_size;
    const float* word_emb = (const float*)d_in[0];
    const int*   num_ids  = (const int*)d_in[1];
    const int*   is_resp  = (const int*)d_in[2];
    const float* numbers  = (const float*)d_in[3];
    const float* w_alpha  = (const float*)d_in[4];
    const float* b_alpha  = (const float*)d_in[5];
    const float* w_f      = (const float*)d_in[6];
    const float* b_f      = (const float*)d_in[7];
    const float* W_r      = (const float*)d_in[8];
    float* out = (float*)d_out;

    char* ws = (char*)d_ws;
    bf16*  Aws     = (bf16*)(ws);                    // [2176][5120] = 22,282,240 B
    bf16*  Wt      = (bf16*)(ws + 22282240);         // [2][5][1024][1024] = 20,971,520 B
    float* ascaled = (float*)(ws + 52166656);
    int*   sigma   = (int*)(ws + 52174848);
    int*   newgrp  = (int*)(ws + 52183040);
    int*   respv   = (int*)(ws + 52191232);
    float* denom   = (float*)(ws + 52199424);
    int*   aperm   = (int*)(ws + 52199488);          // [2176]
    int*   iperm   = (int*)(ws + 52208192);          // [2048]
    int*   meta    = (int*)(ws + 52216384);          // [4]

    k_sort  <<<16,   128, 0, stream>>>(num_ids, is_resp, numbers, sigma, newgrp, respv, denom);
    k_meta  <<<1,   1024, 0, stream>>>(respv, aperm, iperm, meta);
    k_gather<<<2048, 256, 0, stream>>>(word_emb, num_ids, w_alpha, b_alpha, denom, iperm,
                                       Aws, ascaled);
    k_wtf   <<<4352, 256, 0, stream>>>(W_r, w_f, Wt);
    k_build <<<dim3(16,16), 64, 0, stream>>>(ascaled, sigma, newgrp, respv, iperm, Aws);
    k_gemm  <<<544,  256, 0, stream>>>(Aws, Wt, meta, aperm, b_f, out);
}

// Round 4
// 319.216 us; speedup vs baseline: 1.0925x; 1.0099x over previous
//
#include <hip/hip_runtime.h>
#include <hip/hip_bf16.h>
#include <stdint.h>

#define B_ 16
#define S_ 2048
#define H_ 1024
#define N_ 128
#define M_ (B_*N_)    // 2048
#define K5 5120       // compact: 4 relation slots + Init slot (slot 4)
#define MP 2176       // padded rows: 17 tiles of 128 (class-0 block | class-1 block | pad)

typedef __attribute__((ext_vector_type(8))) short s8vec;   // 8 x bf16 (4 VGPRs)
typedef __attribute__((ext_vector_type(4))) short s4vec;   // 4 x bf16 (2 VGPRs)
typedef __attribute__((ext_vector_type(4))) float f4vec;
typedef __hip_bfloat16 bf16;

// ---------------------------------------------------------------------------
// Kernel 0: per-batch sort by `numbers`, validity count, tie-group flags.
__global__ void k_sort(const int* __restrict__ num_ids, const int* __restrict__ is_resp,
                       const float* __restrict__ numbers,
                       int* __restrict__ sigma, int* __restrict__ newgrp,
                       int* __restrict__ respv, float* __restrict__ denom) {
    int b = blockIdx.x, i = threadIdx.x;
    __shared__ float nums[N_];
    __shared__ int sig[N_];
    __shared__ int cnt;
    float ni = numbers[b*N_ + i];
    int idv = num_ids[b*N_ + i];
    int valid = (idv >= 0) ? 1 : 0;
    nums[i] = ni;
    if (i == 0) cnt = 0;
    __syncthreads();
    int p = 0;
    for (int j = 0; j < N_; ++j) {
        float nj = nums[j];
        p += (nj < ni || (nj == ni && j < i)) ? 1 : 0;   // total order, ties by index
    }
    sig[p] = i;
    atomicAdd(&cnt, valid);
    __syncthreads();
    sigma[b*N_ + i] = sig[i];
    int cur = sig[i];
    int prv = (i > 0) ? sig[i-1] : 0;
    newgrp[b*N_ + i] = (i == 0 || nums[cur] != nums[prv]) ? 1 : 0;
    respv[b*N_ + i] = ((is_resp[b*N_ + i] == 1) ? 1 : 0) | (valid << 1);
    if (i == 0) denom[b] = fmaxf((float)(cnt - 1), 1.0f);
}

// ---------------------------------------------------------------------------
// Kernel 0b: global class partition. Single block, 1024 threads, 2 rows each.
// perm: class-0 rows pack at [0,C0), class-1 at [P0, P0+C1), P0 = ceil128(C0).
__global__ void k_meta(const int* __restrict__ respv, int* __restrict__ aperm,
                       int* __restrict__ iperm, int* __restrict__ meta) {
    __shared__ int s0[1024], s1[1024];
    int t = threadIdx.x;
    aperm[t] = -1; aperm[t + 1024] = -1;
    if (t < MP - 2048) aperm[t + 2048] = -1;
    int r0 = 2*t, r1 = 2*t + 1;
    int c_a = respv[r0] & 1, c_b = respv[r1] & 1;
    int a0 = 1 - c_a, b0 = 1 - c_b;
    s0[t] = a0 + b0;
    s1[t] = c_a + c_b;
    __syncthreads();
    for (int off = 1; off < 1024; off <<= 1) {
        int v0 = (t >= off) ? s0[t-off] : 0;
        int v1 = (t >= off) ? s1[t-off] : 0;
        __syncthreads();
        s0[t] += v0; s1[t] += v1;
        __syncthreads();
    }
    int C0 = s0[1023], C1 = s1[1023];
    int P0 = ((C0 + 127) >> 7) << 7;
    int ex0 = s0[t] - (a0 + b0);     // exclusive prefix over pairs
    int ex1 = s1[t] - (c_a + c_b);
    int p_a = (c_a == 0) ? ex0 : P0 + ex1;
    int p_b = (c_b == 0) ? ex0 + a0 : P0 + ex1 + c_a;
    aperm[p_a] = r0; iperm[r0] = p_a;
    aperm[p_b] = r1; iperm[r1] = p_b;
    if (t == 0) { meta[0] = P0; meta[1] = C0; meta[2] = C1; }
}

// ---------------------------------------------------------------------------
// Kernel 1 (merged prep): three independent jobs in one launch.
//  bid < 2048          : gather Init -> A slot 4, alpha = sigmoid(Init.w_alpha)
//  2048 <= bid < 6144  : W_r -> Wt[class][slot 0..3] bf16 repack
//  6144 <= bid < 6400  : w_f [k][n] -> slot 4 as [n][k], both class stacks
__global__ void k_prep(const float* __restrict__ word_emb, const int* __restrict__ num_ids,
                       const float* __restrict__ w_alpha, const float* __restrict__ b_alpha,
                       const float* __restrict__ denom, const int* __restrict__ iperm,
                       const float* __restrict__ W_r, const float* __restrict__ w_f,
                       bf16* __restrict__ A, float* __restrict__ ascaled,
                       bf16* __restrict__ Wt) {
    __shared__ float lds[64][65];
    int bid = blockIdx.x;
    int t = threadIdx.x;
    if (bid < 2048) {
        // ---- gather + alpha
        int b = bid >> 7, n = bid & 127;
        int idv = num_ids[b*N_ + n];
        int valid = (idv >= 0) ? 1 : 0;
        int idx = idv < 0 ? 0 : (idv > S_-1 ? S_-1 : idv);
        int pr = iperm[b*N_ + n];
        const float4* row = (const float4*)(word_emb + ((size_t)b*S_ + idx)*H_);
        float4 v = row[t];
        float4 w = ((const float4*)w_alpha)[t];
        float part = v.x*w.x + v.y*w.y + v.z*w.z + v.w*w.w;
        union { s4vec v4; bf16 h[4]; } pk;
        pk.h[0] = __float2bfloat16(v.x);
        pk.h[1] = __float2bfloat16(v.y);
        pk.h[2] = __float2bfloat16(v.z);
        pk.h[3] = __float2bfloat16(v.w);
        *(s4vec*)(A + (size_t)pr*K5 + 4*H_ + t*4) = pk.v4;
#pragma unroll
        for (int off = 32; off > 0; off >>= 1) part += __shfl_down(part, off, 64);
        if ((t & 63) == 0) lds[0][t >> 6] = part;
        __syncthreads();
        if (t == 0) {
            float dot = lds[0][0] + lds[0][1] + lds[0][2] + lds[0][3] + b_alpha[0];
            float al = 1.0f / (1.0f + __expf(-dot));
            ascaled[b*N_ + n] = valid ? (al / denom[b]) : 0.0f;
        }
        return;
    }
    if (bid < 6144) {
        // ---- W_r repack: r = 4*(s>>1) + 2*c + (s&1); 8 elems/thread, 16B store.
        size_t o = ((size_t)(bid - 2048)*256 + t)*8;       // over 2*4*H*H elems
        int cs = (int)(o >> 20);                           // H*H = 2^20
        int c = cs >> 2, s = cs & 3;
        int r = ((s >> 1) << 2) + 2*c + (s & 1);
        size_t off = o & (size_t)(H_*H_ - 1);
        const float4* src = (const float4*)(W_r + (size_t)r*H_*H_ + off);
        float4 v0 = src[0], v1 = src[1];
        union { s8vec v8; bf16 h[8]; } pk;
        pk.h[0] = __float2bfloat16(v0.x); pk.h[1] = __float2bfloat16(v0.y);
        pk.h[2] = __float2bfloat16(v0.z); pk.h[3] = __float2bfloat16(v0.w);
        pk.h[4] = __float2bfloat16(v1.x); pk.h[5] = __float2bfloat16(v1.y);
        pk.h[6] = __float2bfloat16(v1.z); pk.h[7] = __float2bfloat16(v1.w);
        *(s8vec*)(Wt + (size_t)(c*5 + s)*H_*H_ + off) = pk.v8;
        return;
    }
    // ---- w_f transpose into slot 4 of both class stacks.
    int bb = bid - 6144;
    int bi = bb & 15, bj = bb >> 4;
    int ty = t >> 4, tx = t & 15;
#pragma unroll
    for (int i = 0; i < 4; ++i) {
        int r = ty*4 + i;                                    // k index within tile
        float4 v = *(const float4*)(w_f + (size_t)(bi*64 + r)*H_ + bj*64 + tx*4);
        lds[r][tx*4+0] = v.x; lds[r][tx*4+1] = v.y;
        lds[r][tx*4+2] = v.z; lds[r][tx*4+3] = v.w;
    }
    __syncthreads();
    bf16* d0 = Wt + (size_t)4*H_*H_;        // class 0 slot 4
    bf16* d1 = Wt + (size_t)9*H_*H_;        // class 1 slot 4
#pragma unroll
    for (int i = 0; i < 4; ++i) {
        int n = ty*4 + i;
        size_t doff = (size_t)(bj*64 + n)*H_ + bi*64 + tx*4;
        union { s4vec v4; bf16 h[4]; } pk;
#pragma unroll
        for (int j = 0; j < 4; ++j) pk.h[j] = __float2bfloat16(lds[tx*4+j][n]);
        *(s4vec*)(d0 + doff) = pk.v4;
        *(s4vec*)(d1 + doff) = pk.v4;
    }
}

// ---------------------------------------------------------------------------
// Kernel 3: build A slots 0-3 via prefix sums over sorted order. Rolling form;
// partial unroll 8 so independent global loads pipeline.
__global__ void k_build(const float* __restrict__ ascaled, const int* __restrict__ sigma,
                        const int* __restrict__ newgrp, const int* __restrict__ respv,
                        const int* __restrict__ iperm, bf16* __restrict__ A) {
    int b = blockIdx.y;
    int h = blockIdx.x*64 + threadIdx.x;
    __shared__ float as_s[N_];
    __shared__ int sig_s[N_], ng_s[N_], rv_s[N_], pm_s[N_];
    for (int j = threadIdx.x; j < N_; j += 64) {
        as_s[j] = ascaled[b*N_ + j];
        sig_s[j] = sigma[b*N_ + j];
        ng_s[j] = newgrp[b*N_ + j];
        rv_s[j] = respv[b*N_ + j];
        pm_s[j] = iperm[b*N_ + j];
    }
    __syncthreads();
    const bf16* initcol = A + 4*H_ + h;          // + pr*K5
    float tot0 = 0.f, tot1 = 0.f;
#pragma unroll 8
    for (int i2 = 0; i2 < N_; ++i2) {
        float v = as_s[i2] * __bfloat162float(initcol[(size_t)pm_s[i2]*K5]);
        if (rv_s[i2] & 1) tot1 += v; else tot0 += v;
    }
    float cS0=0.f, cS1=0.f, cG0=0.f, cG1=0.f;   // strict prefix + current tie group
#pragma unroll 8
    for (int p = 0; p < N_; ++p) {
        int i2 = sig_s[p];
        if (ng_s[p]) { cS0 += cG0; cS1 += cG1; cG0 = 0.f; cG1 = 0.f; }
        float v = as_s[i2] * __bfloat162float(initcol[(size_t)pm_s[i2]*K5]);
        int resp = rv_s[i2] & 1;
        float vf = (rv_s[i2] >> 1) ? 1.0f : 0.0f;
        float G0 = cS0, G1 = cS1;                    // senders with num_j < num_i
        float L0 = tot0 - G0 - (resp ? 0.f : v);     // num_j >= num_i, j != i
        float L1 = tot1 - G1 - (resp ? v : 0.f);
        bf16* Ar = A + (size_t)pm_s[i2]*K5 + h;
        Ar[0*H_] = __float2bfloat16(L0*vf);
        Ar[1*H_] = __float2bfloat16(L1*vf);
        Ar[2*H_] = __float2bfloat16(G0*vf);
        Ar[3*H_] = __float2bfloat16(G1*vf);
        if (resp) cG1 += v; else cG0 += v;
    }
}

// ---------------------------------------------------------------------------
// Kernel 4: GEMM out[2176,1024] = A[2176,5120] x Wt_class^T, fused epilogue.
// 64x64 tiles -> 544 blocks. Proven "minimum 2-phase" schedule (T3 recipe):
//   per step: STAGE(next buf) FIRST; COMPUTE(cur buf); ONE vmcnt(0)+s_barrier
//   at step END. Stage loads fly under the whole ds_read+MFMA phase; the only
//   drain is at the step boundary. Hazards: end-of-step barrier => all waves'
//   ds_reads of the to-be-overwritten buffer already landed in registers
//   (compiler lgkm waits precede the MFMAs); vmcnt(0)+barrier => staged LDS
//   data visible to all waves. 2 buffer pairs = 32 KB -> up to 5 blocks/CU.
// XOR piece swizzle (0 conflicts measured). XCD swizzle: 544 = 8x68.
#define BM 64
#define BN 64
#define BK 64
#define NSTEP (K5/BK)   // 80

__global__ __launch_bounds__(256, 4) void k_gemm(const bf16* __restrict__ A,
                                                 const bf16* __restrict__ Wt,
                                                 const int* __restrict__ meta,
                                                 const int* __restrict__ aperm,
                                                 const float* __restrict__ b_f,
                                                 float* __restrict__ out) {
    __shared__ __align__(16) bf16 As0[BM*BK], As1[BM*BK];   // 8 KB each
    __shared__ __align__(16) bf16 Bs0[BN*BK], Bs1[BN*BK];
    int tid = threadIdx.x;
    int w = tid >> 6, lane = tid & 63;
    int q = lane >> 4, r = lane & 15;
    int bid = blockIdx.x;
    int wg = (bid & 7)*68 + (bid >> 3);      // 544 = 8x68 bijective; XCD x -> nt in {2x,2x+1}
    int mt = wg % 34, nt = wg / 34;
    int rowBase = mt * BM, colBase = nt * BN;
    int wm = w >> 1, wn = w & 1;             // wave tile 32x32
    int P0 = meta[0];
    const bf16* Wtc = Wt + ((rowBase >= P0) ? (size_t)5*H_*H_ : 0);

    // ---- epilogue operands loaded up front and pinned.
    int og[2][4];
    float bias[2];
#pragma unroll
    for (int mi = 0; mi < 2; ++mi) {
        int rb = rowBase + wm*32 + mi*16 + q*4;
#pragma unroll
        for (int e = 0; e < 4; ++e) og[mi][e] = aperm[rb + e];
    }
#pragma unroll
    for (int ni = 0; ni < 2; ++ni) bias[ni] = b_f[colBase + wn*32 + ni*16 + r];
#pragma unroll
    for (int mi = 0; mi < 2; ++mi)
#pragma unroll
        for (int e = 0; e < 4; ++e) asm volatile("" : "+v"(og[mi][e]));
    asm volatile("" : "+v"(bias[0]), "+v"(bias[1]));

    f4vec acc[2][2];
#pragma unroll
    for (int mi = 0; mi < 2; ++mi)
#pragma unroll
        for (int ni = 0; ni < 2; ++ni)
#pragma unroll
            for (int e = 0; e < 4; ++e) acc[mi][ni][e] = 0.0f;

    auto STAGE = [&](bf16* AsB, bf16* BsB, int kin) {
        int slot = kin >> 10, koff = kin & 1023;
        const bf16* Wslot = Wtc + ((size_t)slot << 20);
#pragma unroll
        for (int j = 0; j < 2; ++j) {
            int c = tid + j*256;              // chunk id 0..511 (16B each)
            int row = c >> 3;
            int p = (c & 7) ^ (row & 7);      // global piece -> LDS slot c&7
            const bf16* ga = A + (size_t)(rowBase + row)*K5 + kin + p*8;
            __builtin_amdgcn_global_load_lds((const __attribute__((address_space(1))) void*)ga,
                (__attribute__((address_space(3))) void*)((char*)AsB + j*4096 + w*1024), 16, 0, 0);
            const bf16* gb = Wslot + ((size_t)(colBase + row) << 10) + koff + p*8;
            __builtin_amdgcn_global_load_lds((const __attribute__((address_space(1))) void*)gb,
                (__attribute__((address_space(3))) void*)((char*)BsB + j*4096 + w*1024), 16, 0, 0);
        }
    };

    auto COMPUTE = [&](const bf16* AsB, const bf16* BsB) {
        const short* Asp = (const short*)AsB;
        const short* Bsp = (const short*)BsB;
        s8vec af[2][2], bfr[2][2];
#pragma unroll
        for (int kk = 0; kk < 2; ++kk) {
            int sl = ((kk*4 + q) ^ (r & 7)) << 3;    // slot = piece ^ (row&7), row&7 = r&7
#pragma unroll
            for (int mi = 0; mi < 2; ++mi)
                af[kk][mi] = *(const s8vec*)(Asp + (wm*32 + mi*16 + r)*BK + sl);
#pragma unroll
            for (int ni = 0; ni < 2; ++ni)
                bfr[kk][ni] = *(const s8vec*)(Bsp + (wn*32 + ni*16 + r)*BK + sl);
        }
#pragma unroll
        for (int kk = 0; kk < 2; ++kk)
#pragma unroll
            for (int mi = 0; mi < 2; ++mi)
#pragma unroll
                for (int ni = 0; ni < 2; ++ni)
                    acc[mi][ni] = __builtin_amdgcn_mfma_f32_16x16x32_bf16(
                        af[kk][mi], bfr[kk][ni], acc[mi][ni], 0, 0, 0);
    };

    // prologue: stage tile 0, drain, barrier.
    STAGE(As0, Bs0, 0);
    asm volatile("s_waitcnt vmcnt(0)" ::: "memory");
    __builtin_amdgcn_s_barrier();
    __builtin_amdgcn_sched_barrier(0);

    bf16 *cA = As0, *cB = Bs0, *nA = As1, *nB = Bs1;
    for (int t = 0; t < NSTEP; ++t) {
        if (t + 1 < NSTEP) STAGE(nA, nB, (t + 1)*BK);   // issue BEFORE compute
        COMPUTE(cA, cB);
        asm volatile("s_waitcnt vmcnt(0)" ::: "memory"); // own stage landed
        __builtin_amdgcn_s_barrier();                    // all waves' stage landed
        __builtin_amdgcn_sched_barrier(0);               // nothing hoists above
        bf16* tA = cA; cA = nA; nA = tA;
        bf16* tB = cB; cB = nB; nB = tB;
    }

    // Fused epilogue: bias + relu + aperm row-scatter. Pad rows skipped.
#pragma unroll
    for (int mi = 0; mi < 2; ++mi) {
#pragma unroll
        for (int ni = 0; ni < 2; ++ni) {
            int cc = colBase + wn*32 + ni*16 + r;          // D col = lane&15
            if (og[mi][0] >= 0) out[(size_t)og[mi][0]*H_ + cc] = fmaxf(acc[mi][ni][0] + bias[ni], 0.0f);
            if (og[mi][1] >= 0) out[(size_t)og[mi][1]*H_ + cc] = fmaxf(acc[mi][ni][1] + bias[ni], 0.0f);
            if (og[mi][2] >= 0) out[(size_t)og[mi][2]*H_ + cc] = fmaxf(acc[mi][ni][2] + bias[ni], 0.0f);
            if (og[mi][3] >= 0) out[(size_t)og[mi][3]*H_ + cc] = fmaxf(acc[mi][ni][3] + bias[ni], 0.0f);
        }
    }
}

// ---------------------------------------------------------------------------
extern "C" void kernel_launch(void* const* d_in, const int* in_sizes, int n_in,
                              void* d_out, int out_size, void* d_ws, size_t ws_size,
                              hipStream_t stream) {
    (void)in_sizes; (void)n_in; (void)out_size; (void)ws_size;
    const float* word_emb = (const float*)d_in[0];
    const int*   num_ids  = (const int*)d_in[1];
    const int*   is_resp  = (const int*)d_in[2];
    const float* numbers  = (const float*)d_in[3];
    const float* w_alpha  = (const float*)d_in[4];
    const float* b_alpha  = (const float*)d_in[5];
    const float* w_f      = (const float*)d_in[6];
    const float* b_f      = (const float*)d_in[7];
    const float* W_r      = (const float*)d_in[8];
    float* out = (float*)d_out;

    char* ws = (char*)d_ws;
    bf16*  Aws     = (bf16*)(ws);                    // [2176][5120] = 22,282,240 B
    bf16*  Wt      = (bf16*)(ws + 22282240);         // [2][5][1024][1024] = 20,971,520 B
    float* ascaled = (float*)(ws + 52166656);
    int*   sigma   = (int*)(ws + 52174848);
    int*   newgrp  = (int*)(ws + 52183040);
    int*   respv   = (int*)(ws + 52191232);
    float* denom   = (float*)(ws + 52199424);
    int*   aperm   = (int*)(ws + 52199488);          // [2176]
    int*   iperm   = (int*)(ws + 52208192);          // [2048]
    int*   meta    = (int*)(ws + 52216384);          // [4]

    k_sort  <<<16,   128, 0, stream>>>(num_ids, is_resp, numbers, sigma, newgrp, respv, denom);
    k_meta  <<<1,   1024, 0, stream>>>(respv, aperm, iperm, meta);
    k_prep  <<<6400, 256, 0, stream>>>(word_emb, num_ids, w_alpha, b_alpha, denom, iperm,
                                       W_r, w_f, Aws, ascaled, Wt);
    k_build <<<dim3(16,16), 64, 0, stream>>>(ascaled, sigma, newgrp, respv, iperm, Aws);
    k_gemm  <<<544,  256, 0, stream>>>(Aws, Wt, meta, aperm, b_f, out);
}

// Round 5
// 309.365 us; speedup vs baseline: 1.1273x; 1.0318x over previous
//
#include <hip/hip_runtime.h>
#include <hip/hip_bf16.h>
#include <stdint.h>

#define B_ 16
#define S_ 2048
#define H_ 1024
#define N_ 128
#define M_ (B_*N_)    // 2048
#define K5 5120       // compact: 4 relation slots + Init slot (slot 4)
#define MP 2176       // padded rows: 17 tiles of 128 (class-0 block | class-1 block | pad)

typedef __attribute__((ext_vector_type(8))) short s8vec;   // 8 x bf16 (4 VGPRs)
typedef __attribute__((ext_vector_type(4))) short s4vec;   // 4 x bf16 (2 VGPRs)
typedef __attribute__((ext_vector_type(4))) float f4vec;
typedef __hip_bfloat16 bf16;

// ---------------------------------------------------------------------------
// Kernel 0: per-batch sort by `numbers`, validity count, tie-group flags.
__global__ void k_sort(const int* __restrict__ num_ids, const int* __restrict__ is_resp,
                       const float* __restrict__ numbers,
                       int* __restrict__ sigma, int* __restrict__ newgrp,
                       int* __restrict__ respv, float* __restrict__ denom) {
    int b = blockIdx.x, i = threadIdx.x;
    __shared__ float nums[N_];
    __shared__ int sig[N_];
    __shared__ int cnt;
    float ni = numbers[b*N_ + i];
    int idv = num_ids[b*N_ + i];
    int valid = (idv >= 0) ? 1 : 0;
    nums[i] = ni;
    if (i == 0) cnt = 0;
    __syncthreads();
    int p = 0;
    for (int j = 0; j < N_; ++j) {
        float nj = nums[j];
        p += (nj < ni || (nj == ni && j < i)) ? 1 : 0;   // total order, ties by index
    }
    sig[p] = i;
    atomicAdd(&cnt, valid);
    __syncthreads();
    sigma[b*N_ + i] = sig[i];
    int cur = sig[i];
    int prv = (i > 0) ? sig[i-1] : 0;
    newgrp[b*N_ + i] = (i == 0 || nums[cur] != nums[prv]) ? 1 : 0;
    respv[b*N_ + i] = ((is_resp[b*N_ + i] == 1) ? 1 : 0) | (valid << 1);
    if (i == 0) denom[b] = fmaxf((float)(cnt - 1), 1.0f);
}

// ---------------------------------------------------------------------------
// Kernel 0b: global class partition. Single block, 1024 threads, 2 rows each.
// perm: class-0 rows pack at [0,C0), class-1 at [P0, P0+C1), P0 = ceil128(C0).
__global__ void k_meta(const int* __restrict__ respv, int* __restrict__ aperm,
                       int* __restrict__ iperm, int* __restrict__ meta) {
    __shared__ int s0[1024], s1[1024];
    int t = threadIdx.x;
    aperm[t] = -1; aperm[t + 1024] = -1;
    if (t < MP - 2048) aperm[t + 2048] = -1;
    int r0 = 2*t, r1 = 2*t + 1;
    int c_a = respv[r0] & 1, c_b = respv[r1] & 1;
    int a0 = 1 - c_a, b0 = 1 - c_b;
    s0[t] = a0 + b0;
    s1[t] = c_a + c_b;
    __syncthreads();
    for (int off = 1; off < 1024; off <<= 1) {
        int v0 = (t >= off) ? s0[t-off] : 0;
        int v1 = (t >= off) ? s1[t-off] : 0;
        __syncthreads();
        s0[t] += v0; s1[t] += v1;
        __syncthreads();
    }
    int C0 = s0[1023], C1 = s1[1023];
    int P0 = ((C0 + 127) >> 7) << 7;
    int ex0 = s0[t] - (a0 + b0);     // exclusive prefix over pairs
    int ex1 = s1[t] - (c_a + c_b);
    int p_a = (c_a == 0) ? ex0 : P0 + ex1;
    int p_b = (c_b == 0) ? ex0 + a0 : P0 + ex1 + c_a;
    aperm[p_a] = r0; iperm[r0] = p_a;
    aperm[p_b] = r1; iperm[r1] = p_b;
    if (t == 0) { meta[0] = P0; meta[1] = C0; meta[2] = C1; }
}

// ---------------------------------------------------------------------------
// Kernel 1 (merged prep): three independent jobs in one launch.
//  bid < 2048          : gather Init -> A slot 4, alpha = sigmoid(Init.w_alpha)
//  2048 <= bid < 6144  : W_r -> Wt[class][slot 0..3] bf16 repack
//  6144 <= bid < 6400  : w_f [k][n] -> slot 4 as [n][k], both class stacks
__global__ void k_prep(const float* __restrict__ word_emb, const int* __restrict__ num_ids,
                       const float* __restrict__ w_alpha, const float* __restrict__ b_alpha,
                       const float* __restrict__ denom, const int* __restrict__ iperm,
                       const float* __restrict__ W_r, const float* __restrict__ w_f,
                       bf16* __restrict__ A, float* __restrict__ ascaled,
                       bf16* __restrict__ Wt) {
    __shared__ float lds[64][65];
    int bid = blockIdx.x;
    int t = threadIdx.x;
    if (bid < 2048) {
        // ---- gather + alpha
        int b = bid >> 7, n = bid & 127;
        int idv = num_ids[b*N_ + n];
        int valid = (idv >= 0) ? 1 : 0;
        int idx = idv < 0 ? 0 : (idv > S_-1 ? S_-1 : idv);
        int pr = iperm[b*N_ + n];
        const float4* row = (const float4*)(word_emb + ((size_t)b*S_ + idx)*H_);
        float4 v = row[t];
        float4 w = ((const float4*)w_alpha)[t];
        float part = v.x*w.x + v.y*w.y + v.z*w.z + v.w*w.w;
        union { s4vec v4; bf16 h[4]; } pk;
        pk.h[0] = __float2bfloat16(v.x);
        pk.h[1] = __float2bfloat16(v.y);
        pk.h[2] = __float2bfloat16(v.z);
        pk.h[3] = __float2bfloat16(v.w);
        *(s4vec*)(A + (size_t)pr*K5 + 4*H_ + t*4) = pk.v4;
#pragma unroll
        for (int off = 32; off > 0; off >>= 1) part += __shfl_down(part, off, 64);
        if ((t & 63) == 0) lds[0][t >> 6] = part;
        __syncthreads();
        if (t == 0) {
            float dot = lds[0][0] + lds[0][1] + lds[0][2] + lds[0][3] + b_alpha[0];
            float al = 1.0f / (1.0f + __expf(-dot));
            ascaled[b*N_ + n] = valid ? (al / denom[b]) : 0.0f;
        }
        return;
    }
    if (bid < 6144) {
        // ---- W_r repack: r = 4*(s>>1) + 2*c + (s&1); 8 elems/thread, 16B store.
        size_t o = ((size_t)(bid - 2048)*256 + t)*8;       // over 2*4*H*H elems
        int cs = (int)(o >> 20);                           // H*H = 2^20
        int c = cs >> 2, s = cs & 3;
        int r = ((s >> 1) << 2) + 2*c + (s & 1);
        size_t off = o & (size_t)(H_*H_ - 1);
        const float4* src = (const float4*)(W_r + (size_t)r*H_*H_ + off);
        float4 v0 = src[0], v1 = src[1];
        union { s8vec v8; bf16 h[8]; } pk;
        pk.h[0] = __float2bfloat16(v0.x); pk.h[1] = __float2bfloat16(v0.y);
        pk.h[2] = __float2bfloat16(v0.z); pk.h[3] = __float2bfloat16(v0.w);
        pk.h[4] = __float2bfloat16(v1.x); pk.h[5] = __float2bfloat16(v1.y);
        pk.h[6] = __float2bfloat16(v1.z); pk.h[7] = __float2bfloat16(v1.w);
        *(s8vec*)(Wt + (size_t)(c*5 + s)*H_*H_ + off) = pk.v8;
        return;
    }
    // ---- w_f transpose into slot 4 of both class stacks.
    int bb = bid - 6144;
    int bi = bb & 15, bj = bb >> 4;
    int ty = t >> 4, tx = t & 15;
#pragma unroll
    for (int i = 0; i < 4; ++i) {
        int r = ty*4 + i;                                    // k index within tile
        float4 v = *(const float4*)(w_f + (size_t)(bi*64 + r)*H_ + bj*64 + tx*4);
        lds[r][tx*4+0] = v.x; lds[r][tx*4+1] = v.y;
        lds[r][tx*4+2] = v.z; lds[r][tx*4+3] = v.w;
    }
    __syncthreads();
    bf16* d0 = Wt + (size_t)4*H_*H_;        // class 0 slot 4
    bf16* d1 = Wt + (size_t)9*H_*H_;        // class 1 slot 4
#pragma unroll
    for (int i = 0; i < 4; ++i) {
        int n = ty*4 + i;
        size_t doff = (size_t)(bj*64 + n)*H_ + bi*64 + tx*4;
        union { s4vec v4; bf16 h[4]; } pk;
#pragma unroll
        for (int j = 0; j < 4; ++j) pk.h[j] = __float2bfloat16(lds[tx*4+j][n]);
        *(s4vec*)(d0 + doff) = pk.v4;
        *(s4vec*)(d1 + doff) = pk.v4;
    }
}

// ---------------------------------------------------------------------------
// Kernel 3: build A slots 0-3 via prefix sums over sorted order. Rolling form;
// partial unroll 8 so independent global loads pipeline.
__global__ void k_build(const float* __restrict__ ascaled, const int* __restrict__ sigma,
                        const int* __restrict__ newgrp, const int* __restrict__ respv,
                        const int* __restrict__ iperm, bf16* __restrict__ A) {
    int b = blockIdx.y;
    int h = blockIdx.x*64 + threadIdx.x;
    __shared__ float as_s[N_];
    __shared__ int sig_s[N_], ng_s[N_], rv_s[N_], pm_s[N_];
    for (int j = threadIdx.x; j < N_; j += 64) {
        as_s[j] = ascaled[b*N_ + j];
        sig_s[j] = sigma[b*N_ + j];
        ng_s[j] = newgrp[b*N_ + j];
        rv_s[j] = respv[b*N_ + j];
        pm_s[j] = iperm[b*N_ + j];
    }
    __syncthreads();
    const bf16* initcol = A + 4*H_ + h;          // + pr*K5
    float tot0 = 0.f, tot1 = 0.f;
#pragma unroll 8
    for (int i2 = 0; i2 < N_; ++i2) {
        float v = as_s[i2] * __bfloat162float(initcol[(size_t)pm_s[i2]*K5]);
        if (rv_s[i2] & 1) tot1 += v; else tot0 += v;
    }
    float cS0=0.f, cS1=0.f, cG0=0.f, cG1=0.f;   // strict prefix + current tie group
#pragma unroll 8
    for (int p = 0; p < N_; ++p) {
        int i2 = sig_s[p];
        if (ng_s[p]) { cS0 += cG0; cS1 += cG1; cG0 = 0.f; cG1 = 0.f; }
        float v = as_s[i2] * __bfloat162float(initcol[(size_t)pm_s[i2]*K5]);
        int resp = rv_s[i2] & 1;
        float vf = (rv_s[i2] >> 1) ? 1.0f : 0.0f;
        float G0 = cS0, G1 = cS1;                    // senders with num_j < num_i
        float L0 = tot0 - G0 - (resp ? 0.f : v);     // num_j >= num_i, j != i
        float L1 = tot1 - G1 - (resp ? v : 0.f);
        bf16* Ar = A + (size_t)pm_s[i2]*K5 + h;
        Ar[0*H_] = __float2bfloat16(L0*vf);
        Ar[1*H_] = __float2bfloat16(L1*vf);
        Ar[2*H_] = __float2bfloat16(G0*vf);
        Ar[3*H_] = __float2bfloat16(G1*vf);
        if (resp) cG1 += v; else cG0 += v;
    }
}

// ---------------------------------------------------------------------------
// Kernel 4: GEMM out[2176,1024] = A[2176,5120] x Wt_class^T, fused epilogue.
// IN-BLOCK SPLIT-K: 544 blocks x 512 threads. Waves 0-3 = K half [0,2560),
// waves 4-7 = K half [2560,5120). Each half runs the proven 2-phase schedule
// (STAGE next; COMPUTE cur; vmcnt(0)+s_barrier) on its own 32 KB double
// buffer; 64 KB/block -> 2 blocks/CU -> 16 waves/CU (~4/SIMD) of TLP to
// overlap the per-step drain latency that pinned the 256-thread version at
// 79 us (occupancy 17.5%, all pipes <20%). After the final loop barrier,
// half-1 writes its 16 KB of partial acc to LDS (reuses half-0 staging area:
// all ds_reads were consumed before that barrier), __syncthreads, half-0
// combines and does the fused bias+relu+aperm scatter. No atomics, no extra
// global traffic, no extra launch. XOR piece swizzle unchanged (0 conflicts
// measured). XCD swizzle: 544 = 8x68.
#define BM 64
#define BN 64
#define BK 64
#define KHALF 2560
#define NSTEP (KHALF/BK)   // 40

__global__ __launch_bounds__(512, 4) void k_gemm(const bf16* __restrict__ A,
                                                 const bf16* __restrict__ Wt,
                                                 const int* __restrict__ meta,
                                                 const int* __restrict__ aperm,
                                                 const float* __restrict__ b_f,
                                                 float* __restrict__ out) {
    __shared__ __align__(16) char pool[65536];
    int tid = threadIdx.x;
    int w = tid >> 6, lane = tid & 63;
    int half = w >> 2, wsub = w & 3;         // half: K-split; wsub: wave in half
    int ht = tid & 255;                      // thread id within half
    int hw = ht >> 6;                        // wave id within half (= wsub)
    int q = lane >> 4, r = lane & 15;
    int bid = blockIdx.x;
    int wg = (bid & 7)*68 + (bid >> 3);      // 544 = 8x68 bijective
    int mt = wg % 34, nt = wg / 34;
    int rowBase = mt * BM, colBase = nt * BN;
    int wm = wsub >> 1, wn = wsub & 1;       // wave tile 32x32
    int P0 = meta[0];
    const bf16* Wtc = Wt + ((rowBase >= P0) ? (size_t)5*H_*H_ : 0);
    const int kbase = half * KHALF;

    // per-half LDS staging buffers (32 KB per half)
    bf16* As0 = (bf16*)(pool + half*32768);
    bf16* As1 = (bf16*)(pool + half*32768 +  8192);
    bf16* Bs0 = (bf16*)(pool + half*32768 + 16384);
    bf16* Bs1 = (bf16*)(pool + half*32768 + 24576);

    // ---- epilogue operands (half 0 only), loaded early and pinned.
    int og[2][4];
    float bias[2];
    if (half == 0) {
#pragma unroll
        for (int mi = 0; mi < 2; ++mi) {
            int rb = rowBase + wm*32 + mi*16 + q*4;
#pragma unroll
            for (int e = 0; e < 4; ++e) og[mi][e] = aperm[rb + e];
        }
#pragma unroll
        for (int ni = 0; ni < 2; ++ni) bias[ni] = b_f[colBase + wn*32 + ni*16 + r];
#pragma unroll
        for (int mi = 0; mi < 2; ++mi)
#pragma unroll
            for (int e = 0; e < 4; ++e) asm volatile("" : "+v"(og[mi][e]));
        asm volatile("" : "+v"(bias[0]), "+v"(bias[1]));
    }

    f4vec acc[2][2];
#pragma unroll
    for (int mi = 0; mi < 2; ++mi)
#pragma unroll
        for (int ni = 0; ni < 2; ++ni)
#pragma unroll
            for (int e = 0; e < 4; ++e) acc[mi][ni][e] = 0.0f;

    auto STAGE = [&](bf16* AsB, bf16* BsB, int kin) {
        int slot = kin >> 10, koff = kin & 1023;
        const bf16* Wslot = Wtc + ((size_t)slot << 20);
#pragma unroll
        for (int j = 0; j < 2; ++j) {
            int c = ht + j*256;               // chunk id 0..511 (16B each)
            int row = c >> 3;
            int p = (c & 7) ^ (row & 7);      // global piece -> LDS slot c&7
            const bf16* ga = A + (size_t)(rowBase + row)*K5 + kin + p*8;
            __builtin_amdgcn_global_load_lds((const __attribute__((address_space(1))) void*)ga,
                (__attribute__((address_space(3))) void*)((char*)AsB + j*4096 + hw*1024), 16, 0, 0);
            const bf16* gb = Wslot + ((size_t)(colBase + row) << 10) + koff + p*8;
            __builtin_amdgcn_global_load_lds((const __attribute__((address_space(1))) void*)gb,
                (__attribute__((address_space(3))) void*)((char*)BsB + j*4096 + hw*1024), 16, 0, 0);
        }
    };

    auto COMPUTE = [&](const bf16* AsB, const bf16* BsB) {
        const short* Asp = (const short*)AsB;
        const short* Bsp = (const short*)BsB;
        s8vec af[2][2], bfr[2][2];
#pragma unroll
        for (int kk = 0; kk < 2; ++kk) {
            int sl = ((kk*4 + q) ^ (r & 7)) << 3;    // slot = piece ^ (row&7), row&7 = r&7
#pragma unroll
            for (int mi = 0; mi < 2; ++mi)
                af[kk][mi] = *(const s8vec*)(Asp + (wm*32 + mi*16 + r)*BK + sl);
#pragma unroll
            for (int ni = 0; ni < 2; ++ni)
                bfr[kk][ni] = *(const s8vec*)(Bsp + (wn*32 + ni*16 + r)*BK + sl);
        }
#pragma unroll
        for (int kk = 0; kk < 2; ++kk)
#pragma unroll
            for (int mi = 0; mi < 2; ++mi)
#pragma unroll
                for (int ni = 0; ni < 2; ++ni)
                    acc[mi][ni] = __builtin_amdgcn_mfma_f32_16x16x32_bf16(
                        af[kk][mi], bfr[kk][ni], acc[mi][ni], 0, 0, 0);
    };

    // prologue: each half stages its tile 0, drains its own loads, common barrier.
    STAGE(As0, Bs0, kbase);
    asm volatile("s_waitcnt vmcnt(0)" ::: "memory");
    __builtin_amdgcn_s_barrier();
    __builtin_amdgcn_sched_barrier(0);

    bf16 *cA = As0, *cB = Bs0, *nA = As1, *nB = Bs1;
    for (int t = 0; t < NSTEP; ++t) {
        if (t + 1 < NSTEP) STAGE(nA, nB, kbase + (t + 1)*BK);   // issue BEFORE compute
        COMPUTE(cA, cB);
        asm volatile("s_waitcnt vmcnt(0)" ::: "memory"); // own stage landed
        __builtin_amdgcn_s_barrier();                    // all waves' stage landed
        __builtin_amdgcn_sched_barrier(0);               // nothing hoists above
        bf16* tA = cA; cA = nA; nA = tA;
        bf16* tB = cB; cB = nB; nB = tB;
    }

    // ---- combine halves through LDS (reuse pool[0:16K]; safe after final barrier)
    float* xch = (float*)pool;
    if (half == 1) {
#pragma unroll
        for (int mi = 0; mi < 2; ++mi)
#pragma unroll
            for (int ni = 0; ni < 2; ++ni) {
                int f = (wsub*2 + mi)*2 + ni;            // 0..15
                *(f4vec*)(xch + ((size_t)f*64 + lane)*4) = acc[mi][ni];
            }
    }
    __syncthreads();
    if (half == 0) {
#pragma unroll
        for (int mi = 0; mi < 2; ++mi)
#pragma unroll
            for (int ni = 0; ni < 2; ++ni) {
                int f = (wsub*2 + mi)*2 + ni;
                f4vec o = *(const f4vec*)(xch + ((size_t)f*64 + lane)*4);
#pragma unroll
                for (int e = 0; e < 4; ++e) acc[mi][ni][e] += o[e];
            }
        // Fused epilogue: bias + relu + aperm row-scatter. Pad rows skipped.
#pragma unroll
        for (int mi = 0; mi < 2; ++mi) {
#pragma unroll
            for (int ni = 0; ni < 2; ++ni) {
                int cc = colBase + wn*32 + ni*16 + r;          // D col = lane&15
                if (og[mi][0] >= 0) out[(size_t)og[mi][0]*H_ + cc] = fmaxf(acc[mi][ni][0] + bias[ni], 0.0f);
                if (og[mi][1] >= 0) out[(size_t)og[mi][1]*H_ + cc] = fmaxf(acc[mi][ni][1] + bias[ni], 0.0f);
                if (og[mi][2] >= 0) out[(size_t)og[mi][2]*H_ + cc] = fmaxf(acc[mi][ni][2] + bias[ni], 0.0f);
                if (og[mi][3] >= 0) out[(size_t)og[mi][3]*H_ + cc] = fmaxf(acc[mi][ni][3] + bias[ni], 0.0f);
            }
        }
    }
}

// ---------------------------------------------------------------------------
extern "C" void kernel_launch(void* const* d_in, const int* in_sizes, int n_in,
                              void* d_out, int out_size, void* d_ws, size_t ws_size,
                              hipStream_t stream) {
    (void)in_sizes; (void)n_in; (void)out_size; (void)ws_size;
    const float* word_emb = (const float*)d_in[0];
    const int*   num_ids  = (const int*)d_in[1];
    const int*   is_resp  = (const int*)d_in[2];
    const float* numbers  = (const float*)d_in[3];
    const float* w_alpha  = (const float*)d_in[4];
    const float* b_alpha  = (const float*)d_in[5];
    const float* w_f      = (const float*)d_in[6];
    const float* b_f      = (const float*)d_in[7];
    const float* W_r      = (const float*)d_in[8];
    float* out = (float*)d_out;

    char* ws = (char*)d_ws;
    bf16*  Aws     = (bf16*)(ws);                    // [2176][5120] = 22,282,240 B
    bf16*  Wt      = (bf16*)(ws + 22282240);         // [2][5][1024][1024] = 20,971,520 B
    float* ascaled = (float*)(ws + 52166656);
    int*   sigma   = (int*)(ws + 52174848);
    int*   newgrp  = (int*)(ws + 52183040);
    int*   respv   = (int*)(ws + 52191232);
    float* denom   = (float*)(ws + 52199424);
    int*   aperm   = (int*)(ws + 52199488);          // [2176]
    int*   iperm   = (int*)(ws + 52208192);          // [2048]
    int*   meta    = (int*)(ws + 52216384);          // [4]

    k_sort  <<<16,   128, 0, stream>>>(num_ids, is_resp, numbers, sigma, newgrp, respv, denom);
    k_meta  <<<1,   1024, 0, stream>>>(respv, aperm, iperm, meta);
    k_prep  <<<6400, 256, 0, stream>>>(word_emb, num_ids, w_alpha, b_alpha, denom, iperm,
                                       W_r, w_f, Aws, ascaled, Wt);
    k_build <<<dim3(16,16), 64, 0, stream>>>(ascaled, sigma, newgrp, respv, iperm, Aws);
    k_gemm  <<<544,  512, 0, stream>>>(Aws, Wt, meta, aperm, b_f, out);
}

// Round 6
// 309.264 us; speedup vs baseline: 1.1276x; 1.0003x over previous
//
#include <hip/hip_runtime.h>
#include <hip/hip_bf16.h>
#include <stdint.h>

#define B_ 16
#define S_ 2048
#define H_ 1024
#define N_ 128
#define M_ (B_*N_)    // 2048
#define K5 5120       // compact: 4 relation slots + Init slot (slot 4)
#define MP 2176       // padded rows: 17 tiles of 128 (class-0 block | class-1 block | pad)

typedef __attribute__((ext_vector_type(8))) short s8vec;   // 8 x bf16 (4 VGPRs)
typedef __attribute__((ext_vector_type(4))) short s4vec;   // 4 x bf16 (2 VGPRs)
typedef __attribute__((ext_vector_type(4))) float f4vec;
typedef __hip_bfloat16 bf16;

// ---------------------------------------------------------------------------
// Kernel 0 (merged sort+meta): one block, 1024 threads, thread t owns rows
// g = 2t, 2t+1 (same batch). Per-batch O(N^2) rank sort -> sigma/newgrp/respv/
// denom, then the global class-partition scan (aperm/iperm/meta) in the same
// kernel using the in-register class bits.
__global__ void k_sortmeta(const int* __restrict__ num_ids, const int* __restrict__ is_resp,
                           const float* __restrict__ numbers,
                           int* __restrict__ sigma, int* __restrict__ newgrp,
                           int* __restrict__ respv, float* __restrict__ denom,
                           int* __restrict__ aperm, int* __restrict__ iperm,
                           int* __restrict__ meta) {
    __shared__ float nums_s[2048];
    __shared__ int sig_s[2048];
    __shared__ int s0[1024], s1[1024];
    __shared__ int cnt_s[16];
    int t = threadIdx.x;
    int g0 = 2*t, g1 = 2*t + 1;
    int b = g0 >> 7;
    int i0 = g0 & 127, i1 = g1 & 127;
    float n0 = numbers[g0], n1 = numbers[g1];
    int id0 = num_ids[g0], id1 = num_ids[g1];
    int v0 = (id0 >= 0) ? 1 : 0, v1 = (id1 >= 0) ? 1 : 0;
    int rsp0 = (is_resp[g0] == 1) ? 1 : 0, rsp1 = (is_resp[g1] == 1) ? 1 : 0;
    nums_s[g0] = n0; nums_s[g1] = n1;
    if (t < 16) cnt_s[t] = 0;
    aperm[t] = -1; aperm[t + 1024] = -1;
    if (t < MP - 2048) aperm[t + 2048] = -1;
    __syncthreads();
    // rank sort (ties by index)
    const float* nb = nums_s + b*N_;
    int p0 = 0, p1 = 0;
    for (int j = 0; j < N_; ++j) {
        float nj = nb[j];
        p0 += (nj < n0 || (nj == n0 && j < i0)) ? 1 : 0;
        p1 += (nj < n1 || (nj == n1 && j < i1)) ? 1 : 0;
    }
    sig_s[b*N_ + p0] = i0;
    sig_s[b*N_ + p1] = i1;
    atomicAdd(&cnt_s[b], v0 + v1);
    __syncthreads();
    // outputs
    sigma[g0] = sig_s[g0]; sigma[g1] = sig_s[g1];
    {
        int cur = sig_s[g0];
        int prv = (i0 > 0) ? sig_s[g0-1] : 0;
        newgrp[g0] = (i0 == 0 || nb[cur] != nb[prv]) ? 1 : 0;
        cur = sig_s[g1];
        prv = sig_s[g1-1];
        newgrp[g1] = (nb[cur] != nb[prv]) ? 1 : 0;   // i1 >= 1 always
    }
    respv[g0] = rsp0 | (v0 << 1);
    respv[g1] = rsp1 | (v1 << 1);
    if (t < 16) denom[t] = fmaxf((float)(cnt_s[t] - 1), 1.0f);
    // class partition scan over row pairs (c = resp bit)
    int a0 = 1 - rsp0, b0 = 1 - rsp1;
    s0[t] = a0 + b0;
    s1[t] = rsp0 + rsp1;
    __syncthreads();
    for (int off = 1; off < 1024; off <<= 1) {
        int w0 = (t >= off) ? s0[t-off] : 0;
        int w1 = (t >= off) ? s1[t-off] : 0;
        __syncthreads();
        s0[t] += w0; s1[t] += w1;
        __syncthreads();
    }
    int C0 = s0[1023], C1 = s1[1023];
    int P0 = ((C0 + 127) >> 7) << 7;
    int ex0 = s0[t] - (a0 + b0);     // exclusive prefix over pairs
    int ex1 = s1[t] - (rsp0 + rsp1);
    int p_a = (rsp0 == 0) ? ex0 : P0 + ex1;
    int p_b = (rsp1 == 0) ? ex0 + a0 : P0 + ex1 + rsp0;
    aperm[p_a] = g0; iperm[g0] = p_a;
    aperm[p_b] = g1; iperm[g1] = p_b;
    if (t == 0) { meta[0] = P0; meta[1] = C0; meta[2] = C1; }
}

// ---------------------------------------------------------------------------
// Kernel 1 (merged prep): three independent jobs in one launch.
//  bid < 2048          : gather Init -> A slot 4, alpha = sigmoid(Init.w_alpha)
//  2048 <= bid < 6144  : W_r -> Wt[class][slot 0..3] bf16 repack
//  6144 <= bid < 6400  : w_f [k][n] -> slot 4 as [n][k], both class stacks
__global__ void k_prep(const float* __restrict__ word_emb, const int* __restrict__ num_ids,
                       const float* __restrict__ w_alpha, const float* __restrict__ b_alpha,
                       const float* __restrict__ denom, const int* __restrict__ iperm,
                       const float* __restrict__ W_r, const float* __restrict__ w_f,
                       bf16* __restrict__ A, float* __restrict__ ascaled,
                       bf16* __restrict__ Wt) {
    __shared__ float lds[64][65];
    int bid = blockIdx.x;
    int t = threadIdx.x;
    if (bid < 2048) {
        // ---- gather + alpha
        int b = bid >> 7, n = bid & 127;
        int idv = num_ids[b*N_ + n];
        int valid = (idv >= 0) ? 1 : 0;
        int idx = idv < 0 ? 0 : (idv > S_-1 ? S_-1 : idv);
        int pr = iperm[b*N_ + n];
        const float4* row = (const float4*)(word_emb + ((size_t)b*S_ + idx)*H_);
        float4 v = row[t];
        float4 w = ((const float4*)w_alpha)[t];
        float part = v.x*w.x + v.y*w.y + v.z*w.z + v.w*w.w;
        union { s4vec v4; bf16 h[4]; } pk;
        pk.h[0] = __float2bfloat16(v.x);
        pk.h[1] = __float2bfloat16(v.y);
        pk.h[2] = __float2bfloat16(v.z);
        pk.h[3] = __float2bfloat16(v.w);
        *(s4vec*)(A + (size_t)pr*K5 + 4*H_ + t*4) = pk.v4;
#pragma unroll
        for (int off = 32; off > 0; off >>= 1) part += __shfl_down(part, off, 64);
        if ((t & 63) == 0) lds[0][t >> 6] = part;
        __syncthreads();
        if (t == 0) {
            float dot = lds[0][0] + lds[0][1] + lds[0][2] + lds[0][3] + b_alpha[0];
            float al = 1.0f / (1.0f + __expf(-dot));
            ascaled[b*N_ + n] = valid ? (al / denom[b]) : 0.0f;
        }
        return;
    }
    if (bid < 6144) {
        // ---- W_r repack: r = 4*(s>>1) + 2*c + (s&1); 8 elems/thread, 16B store.
        size_t o = ((size_t)(bid - 2048)*256 + t)*8;       // over 2*4*H*H elems
        int cs = (int)(o >> 20);                           // H*H = 2^20
        int c = cs >> 2, s = cs & 3;
        int r = ((s >> 1) << 2) + 2*c + (s & 1);
        size_t off = o & (size_t)(H_*H_ - 1);
        const float4* src = (const float4*)(W_r + (size_t)r*H_*H_ + off);
        float4 v0 = src[0], v1 = src[1];
        union { s8vec v8; bf16 h[8]; } pk;
        pk.h[0] = __float2bfloat16(v0.x); pk.h[1] = __float2bfloat16(v0.y);
        pk.h[2] = __float2bfloat16(v0.z); pk.h[3] = __float2bfloat16(v0.w);
        pk.h[4] = __float2bfloat16(v1.x); pk.h[5] = __float2bfloat16(v1.y);
        pk.h[6] = __float2bfloat16(v1.z); pk.h[7] = __float2bfloat16(v1.w);
        *(s8vec*)(Wt + (size_t)(c*5 + s)*H_*H_ + off) = pk.v8;
        return;
    }
    // ---- w_f transpose into slot 4 of both class stacks.
    int bb = bid - 6144;
    int bi = bb & 15, bj = bb >> 4;
    int ty = t >> 4, tx = t & 15;
#pragma unroll
    for (int i = 0; i < 4; ++i) {
        int r = ty*4 + i;                                    // k index within tile
        float4 v = *(const float4*)(w_f + (size_t)(bi*64 + r)*H_ + bj*64 + tx*4);
        lds[r][tx*4+0] = v.x; lds[r][tx*4+1] = v.y;
        lds[r][tx*4+2] = v.z; lds[r][tx*4+3] = v.w;
    }
    __syncthreads();
    bf16* d0 = Wt + (size_t)4*H_*H_;        // class 0 slot 4
    bf16* d1 = Wt + (size_t)9*H_*H_;        // class 1 slot 4
#pragma unroll
    for (int i = 0; i < 4; ++i) {
        int n = ty*4 + i;
        size_t doff = (size_t)(bj*64 + n)*H_ + bi*64 + tx*4;
        union { s4vec v4; bf16 h[4]; } pk;
#pragma unroll
        for (int j = 0; j < 4; ++j) pk.h[j] = __float2bfloat16(lds[tx*4+j][n]);
        *(s4vec*)(d0 + doff) = pk.v4;
        *(s4vec*)(d1 + doff) = pk.v4;
    }
}

// ---------------------------------------------------------------------------
// Kernel 3: build A slots 0-3 via prefix sums over sorted order. Rolling form;
// partial unroll 8 so independent global loads pipeline.
__global__ void k_build(const float* __restrict__ ascaled, const int* __restrict__ sigma,
                        const int* __restrict__ newgrp, const int* __restrict__ respv,
                        const int* __restrict__ iperm, bf16* __restrict__ A) {
    int b = blockIdx.y;
    int h = blockIdx.x*64 + threadIdx.x;
    __shared__ float as_s[N_];
    __shared__ int sig_s[N_], ng_s[N_], rv_s[N_], pm_s[N_];
    for (int j = threadIdx.x; j < N_; j += 64) {
        as_s[j] = ascaled[b*N_ + j];
        sig_s[j] = sigma[b*N_ + j];
        ng_s[j] = newgrp[b*N_ + j];
        rv_s[j] = respv[b*N_ + j];
        pm_s[j] = iperm[b*N_ + j];
    }
    __syncthreads();
    const bf16* initcol = A + 4*H_ + h;          // + pr*K5
    float tot0 = 0.f, tot1 = 0.f;
#pragma unroll 8
    for (int i2 = 0; i2 < N_; ++i2) {
        float v = as_s[i2] * __bfloat162float(initcol[(size_t)pm_s[i2]*K5]);
        if (rv_s[i2] & 1) tot1 += v; else tot0 += v;
    }
    float cS0=0.f, cS1=0.f, cG0=0.f, cG1=0.f;   // strict prefix + current tie group
#pragma unroll 8
    for (int p = 0; p < N_; ++p) {
        int i2 = sig_s[p];
        if (ng_s[p]) { cS0 += cG0; cS1 += cG1; cG0 = 0.f; cG1 = 0.f; }
        float v = as_s[i2] * __bfloat162float(initcol[(size_t)pm_s[i2]*K5]);
        int resp = rv_s[i2] & 1;
        float vf = (rv_s[i2] >> 1) ? 1.0f : 0.0f;
        float G0 = cS0, G1 = cS1;                    // senders with num_j < num_i
        float L0 = tot0 - G0 - (resp ? 0.f : v);     // num_j >= num_i, j != i
        float L1 = tot1 - G1 - (resp ? v : 0.f);
        bf16* Ar = A + (size_t)pm_s[i2]*K5 + h;
        Ar[0*H_] = __float2bfloat16(L0*vf);
        Ar[1*H_] = __float2bfloat16(L1*vf);
        Ar[2*H_] = __float2bfloat16(G0*vf);
        Ar[3*H_] = __float2bfloat16(G1*vf);
        if (resp) cG1 += v; else cG0 += v;
    }
}

// ---------------------------------------------------------------------------
// Kernel 4: GEMM out[2176,1024] = A[2176,5120] x Wt_class^T, fused epilogue.
// DEPTH-3 pipeline over 4 STATIC LDS buffer pairs (the round-3 failure was
// pointer-rotated buffers: compiler can't disambiguate ds_read vs in-flight
// global_load_lds -> conservative vmcnt(0) drain every step, depth collapses
// to 1). Static arrays restore alias precision; main loop unrolled x4 so all
// buffer refs are compile-time. Counted waits: steady-state vmcnt(8) keeps
// the 2 newest stages (4 loads each) in flight ACROSS the barrier; stage-t
// data is waited ~3 slots (~900+ cyc) after issue -> L3/HBM latency covered.
// Epilogue slots drain 8/8/4/0. WAR: stage targets the buffer computed in
// the PREVIOUS slot; slot-start barrier guarantees all waves' ds_reads of it
// retired (lgkm waits precede MFMAs precede barrier). RAW: per-wave in-order
// VMEM retirement + uniform schedule => barrier => whole buffer valid.
// LDS 64 KB -> 2 blocks/CU. 544 blocks, XOR piece swizzle (0 conflicts),
// XCD swizzle 544 = 8x68.
#define BM 64
#define BN 64
#define BK 64
#define NSTEP (K5/BK)   // 80

__global__ __launch_bounds__(256, 2) void k_gemm(const bf16* __restrict__ A,
                                                 const bf16* __restrict__ Wt,
                                                 const int* __restrict__ meta,
                                                 const int* __restrict__ aperm,
                                                 const float* __restrict__ b_f,
                                                 float* __restrict__ out) {
    __shared__ __align__(16) bf16 As0[BM*BK], As1[BM*BK], As2[BM*BK], As3[BM*BK];
    __shared__ __align__(16) bf16 Bs0[BN*BK], Bs1[BN*BK], Bs2[BN*BK], Bs3[BN*BK];
    int tid = threadIdx.x;
    int w = tid >> 6, lane = tid & 63;
    int q = lane >> 4, r = lane & 15;
    int bid = blockIdx.x;
    int wg = (bid & 7)*68 + (bid >> 3);      // 544 = 8x68 bijective
    int mt = wg % 34, nt = wg / 34;
    int rowBase = mt * BM, colBase = nt * BN;
    int wm = w >> 1, wn = w & 1;             // wave tile 32x32
    int P0 = meta[0];
    const bf16* Wtc = Wt + ((rowBase >= P0) ? (size_t)5*H_*H_ : 0);

    // ---- epilogue operands loaded up front, pinned, and DRAINED so the main
    // loop's VMEM stream is exactly 4 stage loads per slot.
    int og[2][4];
    float bias[2];
#pragma unroll
    for (int mi = 0; mi < 2; ++mi) {
        int rb = rowBase + wm*32 + mi*16 + q*4;
#pragma unroll
        for (int e = 0; e < 4; ++e) og[mi][e] = aperm[rb + e];
    }
#pragma unroll
    for (int ni = 0; ni < 2; ++ni) bias[ni] = b_f[colBase + wn*32 + ni*16 + r];
#pragma unroll
    for (int mi = 0; mi < 2; ++mi)
#pragma unroll
        for (int e = 0; e < 4; ++e) asm volatile("" : "+v"(og[mi][e]));
    asm volatile("" : "+v"(bias[0]), "+v"(bias[1]));
    asm volatile("s_waitcnt vmcnt(0)" ::: "memory");

    f4vec acc[2][2];
#pragma unroll
    for (int mi = 0; mi < 2; ++mi)
#pragma unroll
        for (int ni = 0; ni < 2; ++ni)
#pragma unroll
            for (int e = 0; e < 4; ++e) acc[mi][ni][e] = 0.0f;

    auto STAGE = [&](bf16* AsB, bf16* BsB, int kin) {
        int slot = kin >> 10, koff = kin & 1023;
        const bf16* Wslot = Wtc + ((size_t)slot << 20);
#pragma unroll
        for (int j = 0; j < 2; ++j) {
            int c = tid + j*256;              // chunk id 0..511 (16B each)
            int row = c >> 3;
            int p = (c & 7) ^ (row & 7);      // global piece -> LDS slot c&7
            const bf16* ga = A + (size_t)(rowBase + row)*K5 + kin + p*8;
            __builtin_amdgcn_global_load_lds((const __attribute__((address_space(1))) void*)ga,
                (__attribute__((address_space(3))) void*)((char*)AsB + j*4096 + w*1024), 16, 0, 0);
            const bf16* gb = Wslot + ((size_t)(colBase + row) << 10) + koff + p*8;
            __builtin_amdgcn_global_load_lds((const __attribute__((address_space(1))) void*)gb,
                (__attribute__((address_space(3))) void*)((char*)BsB + j*4096 + w*1024), 16, 0, 0);
        }
    };

    auto COMPUTE = [&](const bf16* AsB, const bf16* BsB) {
        const short* Asp = (const short*)AsB;
        const short* Bsp = (const short*)BsB;
        s8vec af[2][2], bfr[2][2];
#pragma unroll
        for (int kk = 0; kk < 2; ++kk) {
            int sl = ((kk*4 + q) ^ (r & 7)) << 3;    // slot = piece ^ (row&7), row&7 = r&7
#pragma unroll
            for (int mi = 0; mi < 2; ++mi)
                af[kk][mi] = *(const s8vec*)(Asp + (wm*32 + mi*16 + r)*BK + sl);
#pragma unroll
            for (int ni = 0; ni < 2; ++ni)
                bfr[kk][ni] = *(const s8vec*)(Bsp + (wn*32 + ni*16 + r)*BK + sl);
        }
#pragma unroll
        for (int kk = 0; kk < 2; ++kk)
#pragma unroll
            for (int mi = 0; mi < 2; ++mi)
#pragma unroll
                for (int ni = 0; ni < 2; ++ni)
                    acc[mi][ni] = __builtin_amdgcn_mfma_f32_16x16x32_bf16(
                        af[kk][mi], bfr[kk][ni], acc[mi][ni], 0, 0, 0);
    };

#define SLOT8(CA, CB, SA, SB, tnext)                              \
    asm volatile("s_waitcnt vmcnt(8)" ::: "memory");              \
    __builtin_amdgcn_s_barrier();                                 \
    __builtin_amdgcn_sched_barrier(0);                            \
    STAGE(SA, SB, (tnext)*BK);                                    \
    COMPUTE(CA, CB);                                              \
    __builtin_amdgcn_sched_barrier(0);

    // prologue: stage slots 0,1,2 (12 loads in flight)
    STAGE(As0, Bs0, 0);
    STAGE(As1, Bs1, BK);
    STAGE(As2, Bs2, 2*BK);

    for (int tt = 0; tt < NSTEP - 4; tt += 4) {      // slots 0..75
        SLOT8(As0, Bs0, As3, Bs3, tt + 3);
        SLOT8(As1, Bs1, As0, Bs0, tt + 4);
        SLOT8(As2, Bs2, As1, Bs1, tt + 5);
        SLOT8(As3, Bs3, As2, Bs2, tt + 6);
    }
    // epilogue slots 76..79 (no further staging after slot 76)
    asm volatile("s_waitcnt vmcnt(8)" ::: "memory");   // drains stage 76
    __builtin_amdgcn_s_barrier();
    __builtin_amdgcn_sched_barrier(0);
    STAGE(As3, Bs3, 79*BK);
    COMPUTE(As0, Bs0);
    __builtin_amdgcn_sched_barrier(0);
    asm volatile("s_waitcnt vmcnt(8)" ::: "memory");   // drains stage 77
    __builtin_amdgcn_s_barrier();
    __builtin_amdgcn_sched_barrier(0);
    COMPUTE(As1, Bs1);
    __builtin_amdgcn_sched_barrier(0);
    asm volatile("s_waitcnt vmcnt(4)" ::: "memory");   // drains stage 78
    __builtin_amdgcn_s_barrier();
    __builtin_amdgcn_sched_barrier(0);
    COMPUTE(As2, Bs2);
    __builtin_amdgcn_sched_barrier(0);
    asm volatile("s_waitcnt vmcnt(0)" ::: "memory");   // drains stage 79
    __builtin_amdgcn_s_barrier();
    __builtin_amdgcn_sched_barrier(0);
    COMPUTE(As3, Bs3);
#undef SLOT8

    // Fused epilogue: bias + relu + aperm row-scatter. Pad rows skipped.
#pragma unroll
    for (int mi = 0; mi < 2; ++mi) {
#pragma unroll
        for (int ni = 0; ni < 2; ++ni) {
            int cc = colBase + wn*32 + ni*16 + r;          // D col = lane&15
            if (og[mi][0] >= 0) out[(size_t)og[mi][0]*H_ + cc] = fmaxf(acc[mi][ni][0] + bias[ni], 0.0f);
            if (og[mi][1] >= 0) out[(size_t)og[mi][1]*H_ + cc] = fmaxf(acc[mi][ni][1] + bias[ni], 0.0f);
            if (og[mi][2] >= 0) out[(size_t)og[mi][2]*H_ + cc] = fmaxf(acc[mi][ni][2] + bias[ni], 0.0f);
            if (og[mi][3] >= 0) out[(size_t)og[mi][3]*H_ + cc] = fmaxf(acc[mi][ni][3] + bias[ni], 0.0f);
        }
    }
}

// ---------------------------------------------------------------------------
extern "C" void kernel_launch(void* const* d_in, const int* in_sizes, int n_in,
                              void* d_out, int out_size, void* d_ws, size_t ws_size,
                              hipStream_t stream) {
    (void)in_sizes; (void)n_in; (void)out_size; (void)ws_size;
    const float* word_emb = (const float*)d_in[0];
    const int*   num_ids  = (const int*)d_in[1];
    const int*   is_resp  = (const int*)d_in[2];
    const float* numbers  = (const float*)d_in[3];
    const float* w_alpha  = (const float*)d_in[4];
    const float* b_alpha  = (const float*)d_in[5];
    const float* w_f      = (const float*)d_in[6];
    const float* b_f      = (const float*)d_in[7];
    const float* W_r      = (const float*)d_in[8];
    float* out = (float*)d_out;

    char* ws = (char*)d_ws;
    bf16*  Aws     = (bf16*)(ws);                    // [2176][5120] = 22,282,240 B
    bf16*  Wt      = (bf16*)(ws + 22282240);         // [2][5][1024][1024] = 20,971,520 B
    float* ascaled = (float*)(ws + 52166656);
    int*   sigma   = (int*)(ws + 52174848);
    int*   newgrp  = (int*)(ws + 52183040);
    int*   respv   = (int*)(ws + 52191232);
    float* denom   = (float*)(ws + 52199424);
    int*   aperm   = (int*)(ws + 52199488);          // [2176]
    int*   iperm   = (int*)(ws + 52208192);          // [2048]
    int*   meta    = (int*)(ws + 52216384);          // [4]

    k_sortmeta<<<1, 1024, 0, stream>>>(num_ids, is_resp, numbers, sigma, newgrp, respv,
                                       denom, aperm, iperm, meta);
    k_prep  <<<6400, 256, 0, stream>>>(word_emb, num_ids, w_alpha, b_alpha, denom, iperm,
                                       W_r, w_f, Aws, ascaled, Wt);
    k_build <<<dim3(16,16), 64, 0, stream>>>(ascaled, sigma, newgrp, respv, iperm, Aws);
    k_gemm  <<<544,  256, 0, stream>>>(Aws, Wt, meta, aperm, b_f, out);
}

// Round 7
// 299.607 us; speedup vs baseline: 1.1640x; 1.0322x over previous
//
#include <hip/hip_runtime.h>
#include <hip/hip_bf16.h>
#include <stdint.h>

#define B_ 16
#define S_ 2048
#define H_ 1024
#define N_ 128
#define M_ (B_*N_)    // 2048
#define K5 5120       // compact: 4 relation slots + Init slot (slot 4)
#define MP 2176       // padded rows: 17 tiles of 128 (class-0 block | class-1 block | pad)

typedef __attribute__((ext_vector_type(8))) short s8vec;   // 8 x bf16 (4 VGPRs)
typedef __attribute__((ext_vector_type(4))) short s4vec;   // 4 x bf16 (2 VGPRs)
typedef __attribute__((ext_vector_type(4))) float f4vec;
typedef __hip_bfloat16 bf16;

// ---------------------------------------------------------------------------
// Kernel 0 (merged sort+meta): one block, 1024 threads, thread t owns rows
// g = 2t, 2t+1 (same batch). Per-batch O(N^2) rank sort -> sigma/newgrp/respv/
// denom, then the global class-partition scan (aperm/iperm/meta) in the same
// kernel using the in-register class bits.
__global__ void k_sortmeta(const int* __restrict__ num_ids, const int* __restrict__ is_resp,
                           const float* __restrict__ numbers,
                           int* __restrict__ sigma, int* __restrict__ newgrp,
                           int* __restrict__ respv, float* __restrict__ denom,
                           int* __restrict__ aperm, int* __restrict__ iperm,
                           int* __restrict__ meta) {
    __shared__ float nums_s[2048];
    __shared__ int sig_s[2048];
    __shared__ int s0[1024], s1[1024];
    __shared__ int cnt_s[16];
    int t = threadIdx.x;
    int g0 = 2*t, g1 = 2*t + 1;
    int b = g0 >> 7;
    int i0 = g0 & 127, i1 = g1 & 127;
    float n0 = numbers[g0], n1 = numbers[g1];
    int id0 = num_ids[g0], id1 = num_ids[g1];
    int v0 = (id0 >= 0) ? 1 : 0, v1 = (id1 >= 0) ? 1 : 0;
    int rsp0 = (is_resp[g0] == 1) ? 1 : 0, rsp1 = (is_resp[g1] == 1) ? 1 : 0;
    nums_s[g0] = n0; nums_s[g1] = n1;
    if (t < 16) cnt_s[t] = 0;
    aperm[t] = -1; aperm[t + 1024] = -1;
    if (t < MP - 2048) aperm[t + 2048] = -1;
    __syncthreads();
    // rank sort (ties by index)
    const float* nb = nums_s + b*N_;
    int p0 = 0, p1 = 0;
    for (int j = 0; j < N_; ++j) {
        float nj = nb[j];
        p0 += (nj < n0 || (nj == n0 && j < i0)) ? 1 : 0;
        p1 += (nj < n1 || (nj == n1 && j < i1)) ? 1 : 0;
    }
    sig_s[b*N_ + p0] = i0;
    sig_s[b*N_ + p1] = i1;
    atomicAdd(&cnt_s[b], v0 + v1);
    __syncthreads();
    // outputs
    sigma[g0] = sig_s[g0]; sigma[g1] = sig_s[g1];
    {
        int cur = sig_s[g0];
        int prv = (i0 > 0) ? sig_s[g0-1] : 0;
        newgrp[g0] = (i0 == 0 || nb[cur] != nb[prv]) ? 1 : 0;
        cur = sig_s[g1];
        prv = sig_s[g1-1];
        newgrp[g1] = (nb[cur] != nb[prv]) ? 1 : 0;   // i1 >= 1 always
    }
    respv[g0] = rsp0 | (v0 << 1);
    respv[g1] = rsp1 | (v1 << 1);
    if (t < 16) denom[t] = fmaxf((float)(cnt_s[t] - 1), 1.0f);
    // class partition scan over row pairs (c = resp bit)
    int a0 = 1 - rsp0, b0 = 1 - rsp1;
    s0[t] = a0 + b0;
    s1[t] = rsp0 + rsp1;
    __syncthreads();
    for (int off = 1; off < 1024; off <<= 1) {
        int w0 = (t >= off) ? s0[t-off] : 0;
        int w1 = (t >= off) ? s1[t-off] : 0;
        __syncthreads();
        s0[t] += w0; s1[t] += w1;
        __syncthreads();
    }
    int C0 = s0[1023], C1 = s1[1023];
    int P0 = ((C0 + 127) >> 7) << 7;
    int ex0 = s0[t] - (a0 + b0);     // exclusive prefix over pairs
    int ex1 = s1[t] - (rsp0 + rsp1);
    int p_a = (rsp0 == 0) ? ex0 : P0 + ex1;
    int p_b = (rsp1 == 0) ? ex0 + a0 : P0 + ex1 + rsp0;
    aperm[p_a] = g0; iperm[g0] = p_a;
    aperm[p_b] = g1; iperm[g1] = p_b;
    if (t == 0) { meta[0] = P0; meta[1] = C0; meta[2] = C1; }
}

// ---------------------------------------------------------------------------
// Kernel 1 (merged prep): three independent jobs in one launch.
//  bid < 2048          : gather Init -> A slot 4, alpha = sigmoid(Init.w_alpha)
//  2048 <= bid < 6144  : W_r -> Wt[class][slot 0..3] bf16 repack
//  6144 <= bid < 6400  : w_f [k][n] -> slot 4 as [n][k], both class stacks
__global__ void k_prep(const float* __restrict__ word_emb, const int* __restrict__ num_ids,
                       const float* __restrict__ w_alpha, const float* __restrict__ b_alpha,
                       const float* __restrict__ denom, const int* __restrict__ iperm,
                       const float* __restrict__ W_r, const float* __restrict__ w_f,
                       bf16* __restrict__ A, float* __restrict__ ascaled,
                       bf16* __restrict__ Wt) {
    __shared__ float lds[64][65];
    int bid = blockIdx.x;
    int t = threadIdx.x;
    if (bid < 2048) {
        // ---- gather + alpha
        int b = bid >> 7, n = bid & 127;
        int idv = num_ids[b*N_ + n];
        int valid = (idv >= 0) ? 1 : 0;
        int idx = idv < 0 ? 0 : (idv > S_-1 ? S_-1 : idv);
        int pr = iperm[b*N_ + n];
        const float4* row = (const float4*)(word_emb + ((size_t)b*S_ + idx)*H_);
        float4 v = row[t];
        float4 w = ((const float4*)w_alpha)[t];
        float part = v.x*w.x + v.y*w.y + v.z*w.z + v.w*w.w;
        union { s4vec v4; bf16 h[4]; } pk;
        pk.h[0] = __float2bfloat16(v.x);
        pk.h[1] = __float2bfloat16(v.y);
        pk.h[2] = __float2bfloat16(v.z);
        pk.h[3] = __float2bfloat16(v.w);
        *(s4vec*)(A + (size_t)pr*K5 + 4*H_ + t*4) = pk.v4;
#pragma unroll
        for (int off = 32; off > 0; off >>= 1) part += __shfl_down(part, off, 64);
        if ((t & 63) == 0) lds[0][t >> 6] = part;
        __syncthreads();
        if (t == 0) {
            float dot = lds[0][0] + lds[0][1] + lds[0][2] + lds[0][3] + b_alpha[0];
            float al = 1.0f / (1.0f + __expf(-dot));
            ascaled[b*N_ + n] = valid ? (al / denom[b]) : 0.0f;
        }
        return;
    }
    if (bid < 6144) {
        // ---- W_r repack: r = 4*(s>>1) + 2*c + (s&1); 8 elems/thread, 16B store.
        size_t o = ((size_t)(bid - 2048)*256 + t)*8;       // over 2*4*H*H elems
        int cs = (int)(o >> 20);                           // H*H = 2^20
        int c = cs >> 2, s = cs & 3;
        int r = ((s >> 1) << 2) + 2*c + (s & 1);
        size_t off = o & (size_t)(H_*H_ - 1);
        const float4* src = (const float4*)(W_r + (size_t)r*H_*H_ + off);
        float4 v0 = src[0], v1 = src[1];
        union { s8vec v8; bf16 h[8]; } pk;
        pk.h[0] = __float2bfloat16(v0.x); pk.h[1] = __float2bfloat16(v0.y);
        pk.h[2] = __float2bfloat16(v0.z); pk.h[3] = __float2bfloat16(v0.w);
        pk.h[4] = __float2bfloat16(v1.x); pk.h[5] = __float2bfloat16(v1.y);
        pk.h[6] = __float2bfloat16(v1.z); pk.h[7] = __float2bfloat16(v1.w);
        *(s8vec*)(Wt + (size_t)(c*5 + s)*H_*H_ + off) = pk.v8;
        return;
    }
    // ---- w_f transpose into slot 4 of both class stacks.
    int bb = bid - 6144;
    int bi = bb & 15, bj = bb >> 4;
    int ty = t >> 4, tx = t & 15;
#pragma unroll
    for (int i = 0; i < 4; ++i) {
        int r = ty*4 + i;                                    // k index within tile
        float4 v = *(const float4*)(w_f + (size_t)(bi*64 + r)*H_ + bj*64 + tx*4);
        lds[r][tx*4+0] = v.x; lds[r][tx*4+1] = v.y;
        lds[r][tx*4+2] = v.z; lds[r][tx*4+3] = v.w;
    }
    __syncthreads();
    bf16* d0 = Wt + (size_t)4*H_*H_;        // class 0 slot 4
    bf16* d1 = Wt + (size_t)9*H_*H_;        // class 1 slot 4
#pragma unroll
    for (int i = 0; i < 4; ++i) {
        int n = ty*4 + i;
        size_t doff = (size_t)(bj*64 + n)*H_ + bi*64 + tx*4;
        union { s4vec v4; bf16 h[4]; } pk;
#pragma unroll
        for (int j = 0; j < 4; ++j) pk.h[j] = __float2bfloat16(lds[tx*4+j][n]);
        *(s4vec*)(d0 + doff) = pk.v4;
        *(s4vec*)(d1 + doff) = pk.v4;
    }
}

// ---------------------------------------------------------------------------
// Kernel 3: build A slots 0-3 via prefix sums over sorted order. Rolling form;
// partial unroll 8 so independent global loads pipeline.
__global__ void k_build(const float* __restrict__ ascaled, const int* __restrict__ sigma,
                        const int* __restrict__ newgrp, const int* __restrict__ respv,
                        const int* __restrict__ iperm, bf16* __restrict__ A) {
    int b = blockIdx.y;
    int h = blockIdx.x*64 + threadIdx.x;
    __shared__ float as_s[N_];
    __shared__ int sig_s[N_], ng_s[N_], rv_s[N_], pm_s[N_];
    for (int j = threadIdx.x; j < N_; j += 64) {
        as_s[j] = ascaled[b*N_ + j];
        sig_s[j] = sigma[b*N_ + j];
        ng_s[j] = newgrp[b*N_ + j];
        rv_s[j] = respv[b*N_ + j];
        pm_s[j] = iperm[b*N_ + j];
    }
    __syncthreads();
    const bf16* initcol = A + 4*H_ + h;          // + pr*K5
    float tot0 = 0.f, tot1 = 0.f;
#pragma unroll 8
    for (int i2 = 0; i2 < N_; ++i2) {
        float v = as_s[i2] * __bfloat162float(initcol[(size_t)pm_s[i2]*K5]);
        if (rv_s[i2] & 1) tot1 += v; else tot0 += v;
    }
    float cS0=0.f, cS1=0.f, cG0=0.f, cG1=0.f;   // strict prefix + current tie group
#pragma unroll 8
    for (int p = 0; p < N_; ++p) {
        int i2 = sig_s[p];
        if (ng_s[p]) { cS0 += cG0; cS1 += cG1; cG0 = 0.f; cG1 = 0.f; }
        float v = as_s[i2] * __bfloat162float(initcol[(size_t)pm_s[i2]*K5]);
        int resp = rv_s[i2] & 1;
        float vf = (rv_s[i2] >> 1) ? 1.0f : 0.0f;
        float G0 = cS0, G1 = cS1;                    // senders with num_j < num_i
        float L0 = tot0 - G0 - (resp ? 0.f : v);     // num_j >= num_i, j != i
        float L1 = tot1 - G1 - (resp ? v : 0.f);
        bf16* Ar = A + (size_t)pm_s[i2]*K5 + h;
        Ar[0*H_] = __float2bfloat16(L0*vf);
        Ar[1*H_] = __float2bfloat16(L1*vf);
        Ar[2*H_] = __float2bfloat16(G0*vf);
        Ar[3*H_] = __float2bfloat16(G1*vf);
        if (resp) cG1 += v; else cG0 += v;
    }
}

// ---------------------------------------------------------------------------
// Kernel 4: GEMM partials. All 6 prior schedules at 64x64 tiles pinned at
// ~65-79 us because MFMA:ds_read = 1:1 (arithmetic-intensity bound, not
// latency). FIX: BM=BN=128 (per-wave 64x64 -> 32 MFMA : 16 ds_read = 2:1,
// 43.7 FLOP/LDS-byte vs 8.2) with SPLIT-K=4 over private partial buffers
// (plain streaming stores, NO atomics) to keep grid = 17x8x4 = 544 blocks
// (2/CU, 8 waves/CU). 20 steps/block of BK=64. Proven 2-phase schedule with
// STATIC buffer names (no pointer swap): STAGE(next) -> COMPUTE(cur) ->
// vmcnt(0)+s_barrier. LDS = 2 x (16+16) KB = 64 KB -> 2 blocks/CU.
// XOR piece swizzle unchanged (0 conflicts measured; row&7 involution valid
// since 16/64 are multiples of 8). XCD swizzle 544 = 8x68: each XCD gets 4
// consecutive (nt,ks) combos -> B panels 4x320 KB L2-resident.
#define BM 128
#define BN 128
#define BK 64
#define KS 4
#define KSP (K5/KS)        // 1280
#define NSTEP (KSP/BK)     // 20

__global__ __launch_bounds__(256, 2) void k_gemm(const bf16* __restrict__ A,
                                                 const bf16* __restrict__ Wt,
                                                 const int* __restrict__ meta,
                                                 float* __restrict__ P) {
    __shared__ __align__(16) bf16 As0[BM*BK], As1[BM*BK];   // 16 KB each
    __shared__ __align__(16) bf16 Bs0[BN*BK], Bs1[BN*BK];
    int tid = threadIdx.x;
    int w = tid >> 6, lane = tid & 63;
    int q = lane >> 4, r = lane & 15;
    int bid = blockIdx.x;
    int wg = (bid & 7)*68 + (bid >> 3);      // 544 = 8x68 bijective
    int mt = wg % 17;
    int rest = wg / 17;                      // 0..31
    int nt = rest & 7, ks = rest >> 3;
    int rowBase = mt * BM, colBase = nt * BN;
    int wm = w >> 1, wn = w & 1;             // wave tile 64x64
    int P0 = meta[0];
    const bf16* Wtc = Wt + ((rowBase >= P0) ? (size_t)5*H_*H_ : 0);
    const int kb = ks * KSP;

    f4vec acc[4][4];
#pragma unroll
    for (int mi = 0; mi < 4; ++mi)
#pragma unroll
        for (int ni = 0; ni < 4; ++ni)
#pragma unroll
            for (int e = 0; e < 4; ++e) acc[mi][ni][e] = 0.0f;

    // 8 global_load_lds per thread per stage (A x4, B x4).
    auto STAGE = [&](bf16* AsB, bf16* BsB, int kin) {
        int slot = kin >> 10, koff = kin & 1023;
        const bf16* Wslot = Wtc + ((size_t)slot << 20);
#pragma unroll
        for (int j = 0; j < 4; ++j) {
            int c = tid + j*256;              // chunk id 0..1023 (16B each)
            int row = c >> 3;                 // 0..127
            int p = (c & 7) ^ (row & 7);      // global piece -> LDS slot c&7
            const bf16* ga = A + (size_t)(rowBase + row)*K5 + kin + p*8;
            __builtin_amdgcn_global_load_lds((const __attribute__((address_space(1))) void*)ga,
                (__attribute__((address_space(3))) void*)((char*)AsB + j*4096 + w*1024), 16, 0, 0);
            const bf16* gb = Wslot + ((size_t)(colBase + row) << 10) + koff + p*8;
            __builtin_amdgcn_global_load_lds((const __attribute__((address_space(1))) void*)gb,
                (__attribute__((address_space(3))) void*)((char*)BsB + j*4096 + w*1024), 16, 0, 0);
        }
    };

    auto COMPUTE = [&](const bf16* AsB, const bf16* BsB) {
        const short* Asp = (const short*)AsB;
        const short* Bsp = (const short*)BsB;
        s8vec af[2][4], bfr[2][4];
#pragma unroll
        for (int kk = 0; kk < 2; ++kk) {
            int sl = ((kk*4 + q) ^ (r & 7)) << 3;    // slot = piece ^ (row&7), row&7 = r&7
#pragma unroll
            for (int mi = 0; mi < 4; ++mi)
                af[kk][mi] = *(const s8vec*)(Asp + (wm*64 + mi*16 + r)*BK + sl);
#pragma unroll
            for (int ni = 0; ni < 4; ++ni)
                bfr[kk][ni] = *(const s8vec*)(Bsp + (wn*64 + ni*16 + r)*BK + sl);
        }
#pragma unroll
        for (int kk = 0; kk < 2; ++kk)
#pragma unroll
            for (int mi = 0; mi < 4; ++mi)
#pragma unroll
                for (int ni = 0; ni < 4; ++ni)
                    acc[mi][ni] = __builtin_amdgcn_mfma_f32_16x16x32_bf16(
                        af[kk][mi], bfr[kk][ni], acc[mi][ni], 0, 0, 0);
    };

    // prologue
    STAGE(As0, Bs0, kb);
    asm volatile("s_waitcnt vmcnt(0)" ::: "memory");
    __builtin_amdgcn_s_barrier();
    __builtin_amdgcn_sched_barrier(0);

    for (int t = 0; t < NSTEP; t += 2) {                 // NSTEP even
        STAGE(As1, Bs1, kb + (t + 1)*BK);                // t+1 <= 19 always
        COMPUTE(As0, Bs0);
        asm volatile("s_waitcnt vmcnt(0)" ::: "memory");
        __builtin_amdgcn_s_barrier();
        __builtin_amdgcn_sched_barrier(0);
        if (t + 2 < NSTEP) STAGE(As0, Bs0, kb + (t + 2)*BK);
        COMPUTE(As1, Bs1);
        asm volatile("s_waitcnt vmcnt(0)" ::: "memory");
        __builtin_amdgcn_s_barrier();
        __builtin_amdgcn_sched_barrier(0);
    }

    // stream partial tile to P[ks] (f32, no atomics; every (ks,row,col)
    // covered exactly once across the grid).
    float* Pk = P + (size_t)ks*MP*H_;
#pragma unroll
    for (int mi = 0; mi < 4; ++mi) {
#pragma unroll
        for (int ni = 0; ni < 4; ++ni) {
            int cc = colBase + wn*64 + ni*16 + r;
#pragma unroll
            for (int e = 0; e < 4; ++e) {
                int rr = rowBase + wm*64 + mi*16 + q*4 + e;
                Pk[(size_t)rr*H_ + cc] = acc[mi][ni][e];
            }
        }
    }
}

// ---------------------------------------------------------------------------
// Kernel 5: epilogue. out[row] = relu(sum_ks P[ks][iperm[row]] + b_f).
__global__ void k_epi(const float* __restrict__ P, const int* __restrict__ iperm,
                      const float* __restrict__ b_f, float* __restrict__ out) {
    int row = blockIdx.x;
    int pr = iperm[row];
    int t = threadIdx.x;
    float4 v0 = ((const float4*)(P + ((size_t)0*MP + pr)*H_))[t];
    float4 v1 = ((const float4*)(P + ((size_t)1*MP + pr)*H_))[t];
    float4 v2 = ((const float4*)(P + ((size_t)2*MP + pr)*H_))[t];
    float4 v3 = ((const float4*)(P + ((size_t)3*MP + pr)*H_))[t];
    float4 bv = ((const float4*)b_f)[t];
    float4 o;
    o.x = fmaxf(v0.x + v1.x + v2.x + v3.x + bv.x, 0.0f);
    o.y = fmaxf(v0.y + v1.y + v2.y + v3.y + bv.y, 0.0f);
    o.z = fmaxf(v0.z + v1.z + v2.z + v3.z + bv.z, 0.0f);
    o.w = fmaxf(v0.w + v1.w + v2.w + v3.w + bv.w, 0.0f);
    ((float4*)(out + (size_t)row*H_))[t] = o;
}

// ---------------------------------------------------------------------------
extern "C" void kernel_launch(void* const* d_in, const int* in_sizes, int n_in,
                              void* d_out, int out_size, void* d_ws, size_t ws_size,
                              hipStream_t stream) {
    (void)in_sizes; (void)n_in; (void)out_size; (void)ws_size;
    const float* word_emb = (const float*)d_in[0];
    const int*   num_ids  = (const int*)d_in[1];
    const int*   is_resp  = (const int*)d_in[2];
    const float* numbers  = (const float*)d_in[3];
    const float* w_alpha  = (const float*)d_in[4];
    const float* b_alpha  = (const float*)d_in[5];
    const float* w_f      = (const float*)d_in[6];
    const float* b_f      = (const float*)d_in[7];
    const float* W_r      = (const float*)d_in[8];
    float* out = (float*)d_out;

    char* ws = (char*)d_ws;
    bf16*  Aws     = (bf16*)(ws);                    // [2176][5120] = 22,282,240 B
    bf16*  Wt      = (bf16*)(ws + 22282240);         // [2][5][1024][1024] = 20,971,520 B
    float* Pbuf    = (float*)(ws + 43253760);        // [4][2176][1024] f32 = 35,651,584 B
    float* ascaled = (float*)(ws + 78905344);
    int*   sigma   = (int*)(ws + 78913536);
    int*   newgrp  = (int*)(ws + 78921728);
    int*   respv   = (int*)(ws + 78929920);
    float* denom   = (float*)(ws + 78938112);
    int*   aperm   = (int*)(ws + 78938176);          // [2176]
    int*   iperm   = (int*)(ws + 78946880);          // [2048]
    int*   meta    = (int*)(ws + 78955072);          // [4]

    k_sortmeta<<<1, 1024, 0, stream>>>(num_ids, is_resp, numbers, sigma, newgrp, respv,
                                       denom, aperm, iperm, meta);
    k_prep  <<<6400, 256, 0, stream>>>(word_emb, num_ids, w_alpha, b_alpha, denom, iperm,
                                       W_r, w_f, Aws, ascaled, Wt);
    k_build <<<dim3(16,16), 64, 0, stream>>>(ascaled, sigma, newgrp, respv, iperm, Aws);
    k_gemm  <<<544,  256, 0, stream>>>(Aws, Wt, meta, Pbuf);
    k_epi   <<<2048, 256, 0, stream>>>(Pbuf, iperm, b_f, out);
}